// Round 1
// baseline (13141.893 us; speedup 1.0000x reference)
//
#include <hip/hip_runtime.h>

#define N_ 50000
#define E_ 800000
#define T_ 3
#define EPS_ 1e-5f

__device__ __forceinline__ float gelu_f(float x) {
    return 0.5f * x * (1.0f + erff(x * 0.70710678118654752440f));
}

// ---------------- weight prep: Wl/3, mean(Wr), mean(b) ----------------
__global__ void k_prep(const float* __restrict__ Wl, const float* __restrict__ Wr,
                       const float* __restrict__ b, float* wls, float* wra, float* ba) {
    int i = blockIdx.x * 256 + threadIdx.x;
    const float third = 1.0f / 3.0f;
    if (i < 9 * 128 * 128) wls[i] = Wl[i] * third;
    if (i < 3 * 128 * 128) {
        int l = i >> 14, rem = i & 16383;
        const float* p = Wr + l * 3 * 16384 + rem;
        wra[i] = (p[0] + p[16384] + p[32768]) * third;
    }
    if (i < 3 * 128) {
        int l = i >> 7, c = i & 127;
        const float* p = b + l * 3 * 128 + c;
        ba[i] = (p[0] + p[128] + p[256]) * third;
    }
}

// ---------------- per-type degree counts ----------------
__global__ void k_count(const int* __restrict__ EI, float* cnt) {
    int i = blockIdx.x * 256 + threadIdx.x;
    if (i >= T_ * E_) return;
    int t = i / E_, e = i - t * E_;
    int d = EI[(t * 2 + 1) * E_ + e];
    atomicAdd(&cnt[t * N_ + d], 1.0f);
}
__global__ void k_inv(float* cnt) {
    int i = blockIdx.x * 256 + threadIdx.x;
    if (i < T_ * N_) cnt[i] = 1.0f / fmaxf(cnt[i], 1.0f);
}

// ---------------- input LN + MLP (64 -> 256 -> 128) ----------------
__global__ __launch_bounds__(256) void k_inmlp(
    const float* __restrict__ xres, const float* __restrict__ gam, const float* __restrict__ bet,
    const float* __restrict__ W1, const float* __restrict__ b1,
    const float* __restrict__ W2, const float* __restrict__ b2, float* __restrict__ x0) {
    __shared__ float xr[32][68];
    __shared__ float h1[32][260];
    int tid = threadIdx.x;
    int base = blockIdx.x * 32;
    for (int i = 0; i < 2; ++i) {
        int f4 = i * 256 + tid;
        int r = f4 >> 4, c4 = f4 & 15;
        float4 v = make_float4(0.f, 0.f, 0.f, 0.f);
        int gr = base + r;
        if (gr < N_) v = *(const float4*)&xres[gr * 64 + c4 * 4];
        *(float4*)&xr[r][c4 * 4] = v;
    }
    __syncthreads();
    if (tid < 32) {
        int r = tid;
        float s = 0.f;
        for (int k = 0; k < 64; ++k) s += xr[r][k];
        float mu = s * (1.0f / 64.0f);
        float v = 0.f;
        for (int k = 0; k < 64; ++k) { float d = xr[r][k] - mu; v += d * d; }
        float rs = rsqrtf(v * (1.0f / 64.0f) + EPS_);
        for (int k = 0; k < 64; ++k)
            xr[r][k] = (xr[r][k] - mu) * rs * gam[k] + bet[k];
    }
    __syncthreads();
    {   // GEMM1 [32x64]@[64x256] -> gelu -> h1
        int tx = tid & 63, ty = tid >> 6;
        int c0 = tx * 4, r0 = ty * 8;
        float acc[8][4];
        for (int r = 0; r < 8; ++r)
            for (int j = 0; j < 4; ++j) acc[r][j] = b1[c0 + j];
        for (int k0 = 0; k0 < 64; k0 += 4) {
            float4 a[8], w[4];
            for (int r = 0; r < 8; ++r) a[r] = *(const float4*)&xr[r0 + r][k0];
            for (int kk = 0; kk < 4; ++kk) w[kk] = *(const float4*)&W1[(k0 + kk) * 256 + c0];
            for (int kk = 0; kk < 4; ++kk)
                for (int r = 0; r < 8; ++r) {
                    float as = (&a[r].x)[kk];
                    acc[r][0] = fmaf(as, w[kk].x, acc[r][0]);
                    acc[r][1] = fmaf(as, w[kk].y, acc[r][1]);
                    acc[r][2] = fmaf(as, w[kk].z, acc[r][2]);
                    acc[r][3] = fmaf(as, w[kk].w, acc[r][3]);
                }
        }
        for (int r = 0; r < 8; ++r)
            for (int j = 0; j < 4; ++j) h1[r0 + r][c0 + j] = gelu_f(acc[r][j]);
    }
    __syncthreads();
    {   // GEMM2 [32x256]@[256x128] -> gelu -> x0
        int tx = tid & 31, ty = tid >> 5;
        int c0 = tx * 4, r0 = ty * 4;
        float acc[4][4];
        for (int r = 0; r < 4; ++r)
            for (int j = 0; j < 4; ++j) acc[r][j] = b2[c0 + j];
        for (int k0 = 0; k0 < 256; k0 += 4) {
            float4 a[4], w[4];
            for (int r = 0; r < 4; ++r) a[r] = *(const float4*)&h1[r0 + r][k0];
            for (int kk = 0; kk < 4; ++kk) w[kk] = *(const float4*)&W2[(k0 + kk) * 128 + c0];
            for (int kk = 0; kk < 4; ++kk)
                for (int r = 0; r < 4; ++r) {
                    float as = (&a[r].x)[kk];
                    acc[r][0] = fmaf(as, w[kk].x, acc[r][0]);
                    acc[r][1] = fmaf(as, w[kk].y, acc[r][1]);
                    acc[r][2] = fmaf(as, w[kk].z, acc[r][2]);
                    acc[r][3] = fmaf(as, w[kk].w, acc[r][3]);
                }
        }
        for (int r = 0; r < 4; ++r) {
            int gr = base + r0 + r;
            if (gr < N_) {
                float4 v = make_float4(gelu_f(acc[r][0]), gelu_f(acc[r][1]),
                                       gelu_f(acc[r][2]), gelu_f(acc[r][3]));
                *(float4*)&x0[(long)gr * 128 + c0] = v;
            }
        }
    }
}

// ---------------- body GEMMs: y_t = x@(Wl_t/3), acc = x@Wr_avg + b_avg ----------------
__global__ __launch_bounds__(256) void k_gemm4(
    const float* __restrict__ X, int ldx,
    const float* __restrict__ wls_l, const float* __restrict__ wra_l, const float* __restrict__ ba_l,
    float* __restrict__ y, float* __restrict__ acc_out,
    float* cs, float* cq) {
    __shared__ float xs[64][132];
    int tid = threadIdx.x;
    int m = blockIdx.y;
    int base = blockIdx.x * 64;
    if (blockIdx.x == 0 && m == 0 && tid < 128) { cs[tid] = 0.0f; cq[tid] = 0.0f; }
    for (int i = 0; i < 8; ++i) {
        int f4 = i * 256 + tid;
        int r = f4 >> 5, c4 = f4 & 31;
        float4 v = make_float4(0.f, 0.f, 0.f, 0.f);
        int gr = base + r;
        if (gr < N_) v = *(const float4*)&X[(long)gr * ldx + c4 * 4];
        *(float4*)&xs[r][c4 * 4] = v;
    }
    __syncthreads();
    const float* W = (m < 3) ? (wls_l + m * 16384) : wra_l;
    int tx = tid & 31, ty = tid >> 5;
    int c0 = tx * 4, r0 = ty * 8;
    float acc[8][4];
    for (int r = 0; r < 8; ++r)
        for (int j = 0; j < 4; ++j) acc[r][j] = (m == 3) ? ba_l[c0 + j] : 0.0f;
    for (int k0 = 0; k0 < 128; k0 += 4) {
        float4 a[8], w[4];
        for (int r = 0; r < 8; ++r) a[r] = *(const float4*)&xs[r0 + r][k0];
        for (int kk = 0; kk < 4; ++kk) w[kk] = *(const float4*)&W[(k0 + kk) * 128 + c0];
        for (int kk = 0; kk < 4; ++kk)
            for (int r = 0; r < 8; ++r) {
                float as = (&a[r].x)[kk];
                acc[r][0] = fmaf(as, w[kk].x, acc[r][0]);
                acc[r][1] = fmaf(as, w[kk].y, acc[r][1]);
                acc[r][2] = fmaf(as, w[kk].z, acc[r][2]);
                acc[r][3] = fmaf(as, w[kk].w, acc[r][3]);
            }
    }
    float* outp = (m < 3) ? (y + (long)m * N_ * 128) : acc_out;
    for (int r = 0; r < 8; ++r) {
        int gr = base + r0 + r;
        if (gr < N_) {
            float4 v = make_float4(acc[r][0], acc[r][1], acc[r][2], acc[r][3]);
            *(float4*)&outp[(long)gr * 128 + c0] = v;
        }
    }
}

// ---------------- edge scatter: acc[dst] += y_t[src] * inv_cnt_t[dst] ----------------
__global__ __launch_bounds__(256) void k_scatter(
    const int* __restrict__ EI, const float* __restrict__ y,
    const float* __restrict__ inv, float* __restrict__ acc) {
    int tid = threadIdx.x;
    int lane = tid & 63, w = tid >> 6;
    int gw = blockIdx.x * 4 + w;
    int e_id = gw * 2 + (lane >> 5);
    if (e_id >= T_ * E_) return;
    int t = e_id / E_, e = e_id - t * E_;
    int s = EI[(t * 2) * E_ + e];
    int d = EI[(t * 2 + 1) * E_ + e];
    float iv = inv[t * N_ + d];
    int f = (lane & 31) * 4;
    const float4 v = *(const float4*)&y[((long)t * N_ + s) * 128 + f];
    float* ap = &acc[(long)d * 128 + f];
    atomicAdd(ap + 0, v.x * iv);
    atomicAdd(ap + 1, v.y * iv);
    atomicAdd(ap + 2, v.z * iv);
    atomicAdd(ap + 3, v.w * iv);
}

// ---------------- GraphNorm passes ----------------
__global__ __launch_bounds__(256) void k_pass1(const float* __restrict__ acc, float* cs) {
    __shared__ float sd[256];
    int tid = threadIdx.x;
    int c = tid & 127, half = tid >> 7;
    int base = blockIdx.x * 128 + half * 64;
    float s = 0.f;
    for (int i = 0; i < 64; ++i) {
        int r = base + i;
        if (r < N_) s += gelu_f(acc[(long)r * 128 + c]);
    }
    sd[tid] = s;
    __syncthreads();
    if (tid < 128) atomicAdd(&cs[c], sd[tid] + sd[tid + 128]);
}
__global__ __launch_bounds__(256) void k_pass2(const float* __restrict__ acc, const float* __restrict__ cs,
                                               const float* __restrict__ gsc, float* __restrict__ outb,
                                               float* cq) {
    __shared__ float sd[256];
    int tid = threadIdx.x;
    int c = tid & 127, half = tid >> 7;
    int base = blockIdx.x * 128 + half * 64;
    float mean = cs[c] / 50000.0f;
    float sm = gsc[c] * mean;
    float s = 0.f;
    for (int i = 0; i < 64; ++i) {
        int r = base + i;
        if (r < N_) {
            float g = gelu_f(acc[(long)r * 128 + c]);
            float o = g - sm;
            outb[(long)r * 128 + c] = o;
            s += o * o;
        }
    }
    sd[tid] = s;
    __syncthreads();
    if (tid < 128) atomicAdd(&cq[c], sd[tid] + sd[tid + 128]);
}
__global__ __launch_bounds__(256) void k_pass3(const float* __restrict__ outb, const float* __restrict__ cq,
                                               const float* __restrict__ gw, const float* __restrict__ gb,
                                               float* __restrict__ xs_l) {
    int tid = threadIdx.x;
    int c = tid & 127, half = tid >> 7;
    int base = blockIdx.x * 128 + half * 64;
    float var = cq[c] / 50000.0f;
    float mul = rsqrtf(var + EPS_) * gw[c];
    float add = gb[c];
    for (int i = 0; i < 64; ++i) {
        int r = base + i;
        if (r < N_) xs_l[(long)r * 384 + c] = outb[(long)r * 128 + c] * mul + add;
    }
}

// ---------------- head part 1: [N,384]@Wh1 gelu @Wh2 gelu -> h2 ----------------
__global__ __launch_bounds__(128) void k_head1(const float* __restrict__ xsave,
    const float* __restrict__ Wh1, const float* __restrict__ bh1,
    const float* __restrict__ Wh2, const float* __restrict__ bh2,
    float* __restrict__ h2out) {
    __shared__ float inb[32][388];
    __shared__ float h1b[32][104];
    int tid = threadIdx.x;
    int base = blockIdx.x * 32;
    for (int i = 0; i < 24; ++i) {
        int f4 = i * 128 + tid;
        int r = f4 / 96, c4 = f4 - r * 96;
        float4 v = make_float4(0.f, 0.f, 0.f, 0.f);
        int gr = base + r;
        if (gr < N_) v = *(const float4*)&xsave[(long)gr * 384 + c4 * 4];
        *(float4*)&inb[r][c4 * 4] = v;
    }
    __syncthreads();
    int tx = tid & 31, ty = tid >> 5;
    int c0 = tx * 4, r0 = ty * 8;
    bool valid = (c0 < 100);
    {
        float acc[8][4];
        for (int r = 0; r < 8; ++r)
            for (int j = 0; j < 4; ++j) acc[r][j] = valid ? bh1[c0 + j] : 0.f;
        if (valid) {
            for (int k0 = 0; k0 < 384; k0 += 4) {
                float4 a[8], w[4];
                for (int r = 0; r < 8; ++r) a[r] = *(const float4*)&inb[r0 + r][k0];
                for (int kk = 0; kk < 4; ++kk) w[kk] = *(const float4*)&Wh1[(k0 + kk) * 100 + c0];
                for (int kk = 0; kk < 4; ++kk)
                    for (int r = 0; r < 8; ++r) {
                        float as = (&a[r].x)[kk];
                        acc[r][0] = fmaf(as, w[kk].x, acc[r][0]);
                        acc[r][1] = fmaf(as, w[kk].y, acc[r][1]);
                        acc[r][2] = fmaf(as, w[kk].z, acc[r][2]);
                        acc[r][3] = fmaf(as, w[kk].w, acc[r][3]);
                    }
            }
            for (int r = 0; r < 8; ++r)
                for (int j = 0; j < 4; ++j) h1b[r0 + r][c0 + j] = gelu_f(acc[r][j]);
        }
    }
    __syncthreads();
    {
        float acc[8][4];
        for (int r = 0; r < 8; ++r)
            for (int j = 0; j < 4; ++j) acc[r][j] = valid ? bh2[c0 + j] : 0.f;
        if (valid) {
            for (int k0 = 0; k0 < 100; k0 += 4) {
                float4 a[8], w[4];
                for (int r = 0; r < 8; ++r) a[r] = *(const float4*)&h1b[r0 + r][k0];
                for (int kk = 0; kk < 4; ++kk) w[kk] = *(const float4*)&Wh2[(k0 + kk) * 100 + c0];
                for (int kk = 0; kk < 4; ++kk)
                    for (int r = 0; r < 8; ++r) {
                        float as = (&a[r].x)[kk];
                        acc[r][0] = fmaf(as, w[kk].x, acc[r][0]);
                        acc[r][1] = fmaf(as, w[kk].y, acc[r][1]);
                        acc[r][2] = fmaf(as, w[kk].z, acc[r][2]);
                        acc[r][3] = fmaf(as, w[kk].w, acc[r][3]);
                    }
            }
            for (int r = 0; r < 8; ++r) {
                int gr = base + r0 + r;
                if (gr < N_) {
                    float4 v = make_float4(gelu_f(acc[r][0]), gelu_f(acc[r][1]),
                                           gelu_f(acc[r][2]), gelu_f(acc[r][3]));
                    *(float4*)&h2out[(long)gr * 100 + c0] = v;
                }
            }
        }
    }
}

// ---------------- head part 2 + VQ ----------------
__global__ __launch_bounds__(128) void k_head2(const float* __restrict__ h2,
    const float* __restrict__ xAA,
    const float* __restrict__ Wo1, const float* __restrict__ bo1,
    const float* __restrict__ Wo2, const float* __restrict__ bo2,
    const float* __restrict__ Wo3, const float* __restrict__ bo3,
    const float* __restrict__ cb, float* __restrict__ zq, float* __restrict__ loss) {
    __shared__ __align__(16) float smem[13216];
    float* A  = smem;           // [32][124], also reused as C
    float* B  = smem + 3968;    // [32][104]
    float* XF = smem + 7296;    // [32][36]
    float* CB = smem + 8448;    // [128][36]
    float* CC = smem + 13056;   // [128]
    float* SR = smem + 13184;   // [32]
    int tid = threadIdx.x;
    int base = blockIdx.x * 32;
    for (int i = 0; i < 8; ++i) {
        int f4 = i * 128 + tid;
        int k = f4 >> 3, j4 = f4 & 7;
        float4 v = *(const float4*)&cb[k * 32 + j4 * 4];
        *(float4*)&CB[k * 36 + j4 * 4] = v;
    }
    for (int i = 0; i < 7; ++i) {
        int f4 = i * 128 + tid;
        if (f4 < 800) {
            int r = f4 / 25, c4 = f4 - r * 25;
            float4 v = make_float4(0.f, 0.f, 0.f, 0.f);
            int gr = base + r;
            if (gr < N_) v = *(const float4*)&h2[(long)gr * 100 + c4 * 4];
            *(float4*)&A[r * 124 + c4 * 4] = v;
        }
    }
    for (int i = 0; i < 2; ++i) {
        int f4 = i * 128 + tid;
        if (f4 < 160) {
            int r = f4 / 5, c4 = f4 - r * 5;
            float4 v = make_float4(0.f, 0.f, 0.f, 0.f);
            int gr = base + r;
            if (gr < N_) v = *(const float4*)&xAA[(long)gr * 20 + c4 * 4];
            *(float4*)&A[r * 124 + 100 + c4 * 4] = v;
        }
    }
    __syncthreads();
    if (tid < 128) {
        float s = 0.f;
        for (int j = 0; j < 32; ++j) { float v = CB[tid * 36 + j]; s += v * v; }
        CC[tid] = s;
    }
    int tx = tid & 31, ty = tid >> 5;
    int c0 = tx * 4, r0 = ty * 8;
    bool valid = (c0 < 100);
    {   // GEMM: A[32][120] @ Wo1 -> gelu -> B
        float acc[8][4];
        for (int r = 0; r < 8; ++r)
            for (int j = 0; j < 4; ++j) acc[r][j] = valid ? bo1[c0 + j] : 0.f;
        if (valid) {
            for (int k0 = 0; k0 < 120; k0 += 4) {
                float4 a[8], w[4];
                for (int r = 0; r < 8; ++r) a[r] = *(const float4*)&A[(r0 + r) * 124 + k0];
                for (int kk = 0; kk < 4; ++kk) w[kk] = *(const float4*)&Wo1[(k0 + kk) * 100 + c0];
                for (int kk = 0; kk < 4; ++kk)
                    for (int r = 0; r < 8; ++r) {
                        float as = (&a[r].x)[kk];
                        acc[r][0] = fmaf(as, w[kk].x, acc[r][0]);
                        acc[r][1] = fmaf(as, w[kk].y, acc[r][1]);
                        acc[r][2] = fmaf(as, w[kk].z, acc[r][2]);
                        acc[r][3] = fmaf(as, w[kk].w, acc[r][3]);
                    }
            }
        }
        __syncthreads();
        if (valid)
            for (int r = 0; r < 8; ++r)
                for (int j = 0; j < 4; ++j) B[(r0 + r) * 104 + c0 + j] = gelu_f(acc[r][j]);
    }
    __syncthreads();
    {   // GEMM: B @ Wo2 -> gelu -> C (aliased onto A)
        float acc[8][4];
        for (int r = 0; r < 8; ++r)
            for (int j = 0; j < 4; ++j) acc[r][j] = valid ? bo2[c0 + j] : 0.f;
        if (valid) {
            for (int k0 = 0; k0 < 100; k0 += 4) {
                float4 a[8], w[4];
                for (int r = 0; r < 8; ++r) a[r] = *(const float4*)&B[(r0 + r) * 104 + k0];
                for (int kk = 0; kk < 4; ++kk) w[kk] = *(const float4*)&Wo2[(k0 + kk) * 100 + c0];
                for (int kk = 0; kk < 4; ++kk)
                    for (int r = 0; r < 8; ++r) {
                        float as = (&a[r].x)[kk];
                        acc[r][0] = fmaf(as, w[kk].x, acc[r][0]);
                        acc[r][1] = fmaf(as, w[kk].y, acc[r][1]);
                        acc[r][2] = fmaf(as, w[kk].z, acc[r][2]);
                        acc[r][3] = fmaf(as, w[kk].w, acc[r][3]);
                    }
            }
        }
        __syncthreads();
        if (valid)
            for (int r = 0; r < 8; ++r)
                for (int j = 0; j < 4; ++j) A[(r0 + r) * 124 + c0 + j] = gelu_f(acc[r][j]);
    }
    __syncthreads();
    {   // GEMM: C @ Wo3 -> tanh -> XF
        int c0b = (tid & 7) * 4, rg = tid >> 3;
        int r0b = rg * 2;
        float acc[2][4];
        for (int r = 0; r < 2; ++r)
            for (int j = 0; j < 4; ++j) acc[r][j] = bo3[c0b + j];
        for (int k0 = 0; k0 < 100; k0 += 4) {
            float4 a[2], w[4];
            for (int r = 0; r < 2; ++r) a[r] = *(const float4*)&A[(r0b + r) * 124 + k0];
            for (int kk = 0; kk < 4; ++kk) w[kk] = *(const float4*)&Wo3[(k0 + kk) * 32 + c0b];
            for (int kk = 0; kk < 4; ++kk)
                for (int r = 0; r < 2; ++r) {
                    float as = (&a[r].x)[kk];
                    acc[r][0] = fmaf(as, w[kk].x, acc[r][0]);
                    acc[r][1] = fmaf(as, w[kk].y, acc[r][1]);
                    acc[r][2] = fmaf(as, w[kk].z, acc[r][2]);
                    acc[r][3] = fmaf(as, w[kk].w, acc[r][3]);
                }
        }
        for (int r = 0; r < 2; ++r)
            for (int j = 0; j < 4; ++j) XF[(r0b + r) * 36 + c0b + j] = tanhf(acc[r][j]);
    }
    __syncthreads();
    {   // VQ: 4 threads per node, 32 codes each (interleaved k = kk*4+t4)
        int node = tid >> 2, t4 = tid & 3;
        float4 xv[8];
        for (int j4 = 0; j4 < 8; ++j4) xv[j4] = *(const float4*)&XF[node * 36 + j4 * 4];
        float xx = 0.f;
        for (int j4 = 0; j4 < 8; ++j4)
            xx += xv[j4].x * xv[j4].x + xv[j4].y * xv[j4].y + xv[j4].z * xv[j4].z + xv[j4].w * xv[j4].w;
        float best = 3.4e38f;
        int bidx = 0;
        for (int kk = 0; kk < 32; ++kk) {
            int k = kk * 4 + t4;
            const float* cbr = &CB[k * 36];
            float dot = 0.f;
            for (int j4 = 0; j4 < 8; ++j4) {
                float4 cv = *(const float4*)&cbr[j4 * 4];
                dot += cv.x * xv[j4].x + cv.y * xv[j4].y + cv.z * xv[j4].z + cv.w * xv[j4].w;
            }
            float d = fmaf(-2.0f, dot, xx) + CC[k];
            if (d < best) { best = d; bidx = k; }
        }
        for (int off = 1; off < 4; off <<= 1) {
            float ob = __shfl_xor(best, off);
            int oi = __shfl_xor(bidx, off);
            if (ob < best || (ob == best && oi < bidx)) { best = ob; bidx = oi; }
        }
        int gr = base + node;
        if (t4 == 0) {
            float s = 0.f;
            if (gr < N_) {
                const float* q = &CB[bidx * 36];
                for (int j4 = 0; j4 < 8; ++j4) {
                    float4 qv = *(const float4*)&q[j4 * 4];
                    *(float4*)&zq[(long)gr * 32 + j4 * 4] = qv;
                    float4 xvv = xv[j4];
                    float d0 = qv.x - xvv.x, d1 = qv.y - xvv.y, d2 = qv.z - xvv.z, d3 = qv.w - xvv.w;
                    s += d0 * d0 + d1 * d1 + d2 * d2 + d3 * d3;
                }
            }
            SR[node] = s;
        }
    }
    __syncthreads();
    if (tid == 0) {
        float S = 0.f;
        for (int i = 0; i < 32; ++i) S += SR[i];
        atomicAdd(loss, S);
    }
}

__global__ void k_fin(float* dout, const float* loss) {
    if (threadIdx.x == 0 && blockIdx.x == 0)
        dout[(long)N_ * 32] = 1.25f * (loss[0] / 1600000.0f);
}

extern "C" void kernel_launch(void* const* d_in, const int* in_sizes, int n_in,
                              void* d_out, int out_size, void* d_ws, size_t ws_size,
                              hipStream_t stream) {
    const float* x_res = (const float*)d_in[0];
    const float* x_AA  = (const float*)d_in[1];
    const int*   EI    = (const int*)d_in[2];
    const float* ln_g  = (const float*)d_in[3];
    const float* ln_b  = (const float*)d_in[4];
    const float* W1    = (const float*)d_in[5];
    const float* b1    = (const float*)d_in[6];
    const float* W2    = (const float*)d_in[7];
    const float* b2    = (const float*)d_in[8];
    const float* sWl   = (const float*)d_in[9];
    const float* sWr   = (const float*)d_in[10];
    const float* sb    = (const float*)d_in[11];
    const float* gnw   = (const float*)d_in[12];
    const float* gnb   = (const float*)d_in[13];
    const float* gns   = (const float*)d_in[14];
    const float* Wh1   = (const float*)d_in[15];
    const float* bh1   = (const float*)d_in[16];
    const float* Wh2   = (const float*)d_in[17];
    const float* bh2   = (const float*)d_in[18];
    const float* Wo1   = (const float*)d_in[19];
    const float* bo1   = (const float*)d_in[20];
    const float* Wo2   = (const float*)d_in[21];
    const float* bo2   = (const float*)d_in[22];
    const float* Wo3   = (const float*)d_in[23];
    const float* bo3   = (const float*)d_in[24];
    const float* cbk   = (const float*)d_in[25];
    float* out = (float*)d_out;

    float* ws    = (float*)d_ws;
    float* xsave = ws;                               // N*384
    float* x0    = xsave + (size_t)N_ * 384;         // N*128
    float* y     = x0 + (size_t)N_ * 128;            // 3*N*128
    float* acc   = y + (size_t)3 * N_ * 128;         // N*128
    float* wls   = acc + (size_t)N_ * 128;           // 147456
    float* wra   = wls + 147456;                     // 49152
    float* ba    = wra + 49152;                      // 384
    float* cnt   = ba + 384;                         // 3*N
    float* loss  = cnt + 3 * N_;                     // 1
    float* cs    = loss + 1;                         // 128
    float* cq    = cs + 128;                         // 128
    float* outb  = y;                                // reuse y0 (dead after scatter)
    float* h2    = y + (size_t)N_ * 128;             // reuse y1 (dead after body)

    hipMemsetAsync(cnt, 0, (3 * N_ + 1 + 256) * sizeof(float), stream);

    k_prep<<<576, 256, 0, stream>>>(sWl, sWr, sb, wls, wra, ba);
    k_count<<<(T_ * E_ + 255) / 256, 256, 0, stream>>>(EI, cnt);
    k_inv<<<(T_ * N_ + 255) / 256, 256, 0, stream>>>(cnt);
    k_inmlp<<<(N_ + 31) / 32, 256, 0, stream>>>(x_res, ln_g, ln_b, W1, b1, W2, b2, x0);

    for (int l = 0; l < 3; ++l) {
        const float* X = (l == 0) ? x0 : (xsave + (size_t)(l - 1) * 128);
        int ldx = (l == 0) ? 128 : 384;
        k_gemm4<<<dim3((N_ + 63) / 64, 4), 256, 0, stream>>>(X, ldx,
            wls + (size_t)l * 3 * 16384, wra + (size_t)l * 16384, ba + l * 128,
            y, acc, cs, cq);
        k_scatter<<<(T_ * E_ + 7) / 8, 256, 0, stream>>>(EI, y, cnt, acc);
        k_pass1<<<(N_ + 127) / 128, 256, 0, stream>>>(acc, cs);
        k_pass2<<<(N_ + 127) / 128, 256, 0, stream>>>(acc, cs, gns + l * 128, outb, cq);
        k_pass3<<<(N_ + 127) / 128, 256, 0, stream>>>(outb, cq, gnw + l * 128, gnb + l * 128,
                                                      xsave + (size_t)l * 128);
    }
    k_head1<<<(N_ + 31) / 32, 128, 0, stream>>>(xsave, Wh1, bh1, Wh2, bh2, h2);
    k_head2<<<(N_ + 31) / 32, 128, 0, stream>>>(h2, x_AA, Wo1, bo1, Wo2, bo2, Wo3, bo3,
                                                cbk, out, loss);
    k_fin<<<1, 64, 0, stream>>>(out, loss);
}

// Round 2
// 2076.435 us; speedup vs baseline: 6.3291x; 6.3291x over previous
//
#include <hip/hip_runtime.h>

#define N_ 50000
#define E_ 800000
#define T_ 3
#define NG_ (T_ * N_)   // 150000 (type,dst) groups
#define EPS_ 1e-5f

__device__ __forceinline__ float gelu_f(float x) {
    return 0.5f * x * (1.0f + erff(x * 0.70710678118654752440f));
}

// ---------------- weight prep: Wl/3, mean(Wr), mean(b) ----------------
__global__ void k_prep(const float* __restrict__ Wl, const float* __restrict__ Wr,
                       const float* __restrict__ b, float* wls, float* wra, float* ba) {
    int i = blockIdx.x * 256 + threadIdx.x;
    const float third = 1.0f / 3.0f;
    if (i < 9 * 128 * 128) wls[i] = Wl[i] * third;
    if (i < 3 * 128 * 128) {
        int l = i >> 14, rem = i & 16383;
        const float* p = Wr + l * 3 * 16384 + rem;
        wra[i] = (p[0] + p[16384] + p[32768]) * third;
    }
    if (i < 3 * 128) {
        int l = i >> 7, c = i & 127;
        const float* p = b + l * 3 * 128 + c;
        ba[i] = (p[0] + p[128] + p[256]) * third;
    }
}

// ---------------- per-(type,dst) degree counts (int) ----------------
__global__ void k_count(const int* __restrict__ EI, int* cnt) {
    int i = blockIdx.x * 256 + threadIdx.x;
    if (i >= T_ * E_) return;
    int t = i / E_, e = i - t * E_;
    int d = EI[(t * 2 + 1) * E_ + e];
    atomicAdd(&cnt[t * N_ + d], 1);
}

// ---------------- exclusive prefix scan of 150000 counts (1 block) ----------------
__global__ __launch_bounds__(1024) void k_scan(const int* __restrict__ cnt, int* __restrict__ rp) {
    __shared__ int sd[1024];
    int tid = threadIdx.x;
    int beg = tid * 147;
    int end = beg + 147; if (end > NG_) end = NG_;
    int tot = 0;
    for (int i = beg; i < end; ++i) tot += cnt[i];
    sd[tid] = tot;
    __syncthreads();
    for (int off = 1; off < 1024; off <<= 1) {
        int v = (tid >= off) ? sd[tid - off] : 0;
        __syncthreads();
        sd[tid] += v;
        __syncthreads();
    }
    int run = sd[tid] - tot;   // exclusive base for this thread's chunk
    for (int i = beg; i < end; ++i) { rp[i] = run; run += cnt[i]; }
}

// ---------------- counts -> 1/max(cnt,1) in place (reinterpret) ----------------
__global__ void k_inv(const int* __restrict__ cnti, float* __restrict__ inv) {
    int i = blockIdx.x * 256 + threadIdx.x;
    if (i < NG_) {
        int c = cnti[i];
        inv[i] = 1.0f / (float)(c > 0 ? c : 1);
    }
}

// ---------------- CSR placement: row_ptr becomes row END after this ----------------
__global__ void k_place(const int* __restrict__ EI, int* __restrict__ rp, int* __restrict__ csr) {
    int i = blockIdx.x * 256 + threadIdx.x;
    if (i >= T_ * E_) return;
    int t = i / E_, e = i - t * E_;
    int s = EI[(t * 2) * E_ + e];
    int d = EI[(t * 2 + 1) * E_ + e];
    int pos = atomicAdd(&rp[t * N_ + d], 1);
    csr[pos] = s;
}

// ---------------- input LN + MLP (64 -> 256 -> 128) ----------------
__global__ __launch_bounds__(256) void k_inmlp(
    const float* __restrict__ xres, const float* __restrict__ gam, const float* __restrict__ bet,
    const float* __restrict__ W1, const float* __restrict__ b1,
    const float* __restrict__ W2, const float* __restrict__ b2, float* __restrict__ x0) {
    __shared__ float xr[32][68];
    __shared__ float h1[32][260];
    int tid = threadIdx.x;
    int base = blockIdx.x * 32;
    for (int i = 0; i < 2; ++i) {
        int f4 = i * 256 + tid;
        int r = f4 >> 4, c4 = f4 & 15;
        float4 v = make_float4(0.f, 0.f, 0.f, 0.f);
        int gr = base + r;
        if (gr < N_) v = *(const float4*)&xres[gr * 64 + c4 * 4];
        *(float4*)&xr[r][c4 * 4] = v;
    }
    __syncthreads();
    if (tid < 32) {
        int r = tid;
        float s = 0.f;
        for (int k = 0; k < 64; ++k) s += xr[r][k];
        float mu = s * (1.0f / 64.0f);
        float v = 0.f;
        for (int k = 0; k < 64; ++k) { float d = xr[r][k] - mu; v += d * d; }
        float rs = rsqrtf(v * (1.0f / 64.0f) + EPS_);
        for (int k = 0; k < 64; ++k)
            xr[r][k] = (xr[r][k] - mu) * rs * gam[k] + bet[k];
    }
    __syncthreads();
    {   // GEMM1 [32x64]@[64x256] -> gelu -> h1
        int tx = tid & 63, ty = tid >> 6;
        int c0 = tx * 4, r0 = ty * 8;
        float acc[8][4];
        for (int r = 0; r < 8; ++r)
            for (int j = 0; j < 4; ++j) acc[r][j] = b1[c0 + j];
        for (int k0 = 0; k0 < 64; k0 += 4) {
            float4 a[8], w[4];
            for (int r = 0; r < 8; ++r) a[r] = *(const float4*)&xr[r0 + r][k0];
            for (int kk = 0; kk < 4; ++kk) w[kk] = *(const float4*)&W1[(k0 + kk) * 256 + c0];
            for (int kk = 0; kk < 4; ++kk)
                for (int r = 0; r < 8; ++r) {
                    float as = (&a[r].x)[kk];
                    acc[r][0] = fmaf(as, w[kk].x, acc[r][0]);
                    acc[r][1] = fmaf(as, w[kk].y, acc[r][1]);
                    acc[r][2] = fmaf(as, w[kk].z, acc[r][2]);
                    acc[r][3] = fmaf(as, w[kk].w, acc[r][3]);
                }
        }
        for (int r = 0; r < 8; ++r)
            for (int j = 0; j < 4; ++j) h1[r0 + r][c0 + j] = gelu_f(acc[r][j]);
    }
    __syncthreads();
    {   // GEMM2 [32x256]@[256x128] -> gelu -> x0
        int tx = tid & 31, ty = tid >> 5;
        int c0 = tx * 4, r0 = ty * 4;
        float acc[4][4];
        for (int r = 0; r < 4; ++r)
            for (int j = 0; j < 4; ++j) acc[r][j] = b2[c0 + j];
        for (int k0 = 0; k0 < 256; k0 += 4) {
            float4 a[4], w[4];
            for (int r = 0; r < 4; ++r) a[r] = *(const float4*)&h1[r0 + r][k0];
            for (int kk = 0; kk < 4; ++kk) w[kk] = *(const float4*)&W2[(k0 + kk) * 128 + c0];
            for (int kk = 0; kk < 4; ++kk)
                for (int r = 0; r < 4; ++r) {
                    float as = (&a[r].x)[kk];
                    acc[r][0] = fmaf(as, w[kk].x, acc[r][0]);
                    acc[r][1] = fmaf(as, w[kk].y, acc[r][1]);
                    acc[r][2] = fmaf(as, w[kk].z, acc[r][2]);
                    acc[r][3] = fmaf(as, w[kk].w, acc[r][3]);
                }
        }
        for (int r = 0; r < 4; ++r) {
            int gr = base + r0 + r;
            if (gr < N_) {
                float4 v = make_float4(gelu_f(acc[r][0]), gelu_f(acc[r][1]),
                                       gelu_f(acc[r][2]), gelu_f(acc[r][3]));
                *(float4*)&x0[(long)gr * 128 + c0] = v;
            }
        }
    }
}

// ---------------- CSR gather: agg[t][d] = inv * sum_{src} X[src] ----------------
__global__ __launch_bounds__(256) void k_gather(
    const int* __restrict__ rp, const int* __restrict__ csr, const float* __restrict__ inv,
    const float* __restrict__ X, int ldx, float* __restrict__ agg) {
    int tid = threadIdx.x;
    int g = blockIdx.x * 8 + (tid >> 5);
    if (g >= NG_) return;
    int f = (tid & 31) * 4;
    int start = (g == 0) ? 0 : rp[g - 1];
    int end = rp[g];
    float4 s = make_float4(0.f, 0.f, 0.f, 0.f);
    for (int e = start; e < end; ++e) {
        int sn = csr[e];
        const float4 v = *(const float4*)&X[(long)sn * ldx + f];
        s.x += v.x; s.y += v.y; s.z += v.z; s.w += v.w;
    }
    float iv = inv[g];
    float4 o = make_float4(s.x * iv, s.y * iv, s.z * iv, s.w * iv);
    *(float4*)&agg[(long)g * 128 + f] = o;
}

// ---------------- body GEMM: acc = sum_t agg_t@(Wl_t/3) + x@Wr_avg + b_avg ----------------
__global__ __launch_bounds__(256) void k_gemm_body(
    const float* __restrict__ X, int ldx, const float* __restrict__ agg,
    const float* __restrict__ wls_l, const float* __restrict__ wra_l, const float* __restrict__ ba_l,
    float* __restrict__ acc_out, float* cs, float* cq) {
    __shared__ float xs[64][132];
    int tid = threadIdx.x;
    int base = blockIdx.x * 64;
    if (blockIdx.x == 0 && tid < 128) { cs[tid] = 0.0f; cq[tid] = 0.0f; }
    int tx = tid & 31, ty = tid >> 5;
    int c0 = tx * 4, r0 = ty * 8;
    float acc[8][4];
    for (int r = 0; r < 8; ++r)
        for (int j = 0; j < 4; ++j) acc[r][j] = ba_l[c0 + j];
    for (int seg = 0; seg < 4; ++seg) {
        const float* src; long ld;
        if (seg < 3) { src = agg + ((long)seg * N_ + base) * 128; ld = 128; }
        else         { src = X + (long)base * ldx; ld = ldx; }
        __syncthreads();
        for (int i = 0; i < 8; ++i) {
            int f4 = i * 256 + tid;
            int r = f4 >> 5, c4 = f4 & 31;
            float4 v = make_float4(0.f, 0.f, 0.f, 0.f);
            if (base + r < N_) v = *(const float4*)&src[(long)r * ld + c4 * 4];
            *(float4*)&xs[r][c4 * 4] = v;
        }
        __syncthreads();
        const float* W = (seg < 3) ? (wls_l + seg * 16384) : wra_l;
        for (int k0 = 0; k0 < 128; k0 += 4) {
            float4 a[8], w[4];
            for (int r = 0; r < 8; ++r) a[r] = *(const float4*)&xs[r0 + r][k0];
            for (int kk = 0; kk < 4; ++kk) w[kk] = *(const float4*)&W[(k0 + kk) * 128 + c0];
            for (int kk = 0; kk < 4; ++kk)
                for (int r = 0; r < 8; ++r) {
                    float as = (&a[r].x)[kk];
                    acc[r][0] = fmaf(as, w[kk].x, acc[r][0]);
                    acc[r][1] = fmaf(as, w[kk].y, acc[r][1]);
                    acc[r][2] = fmaf(as, w[kk].z, acc[r][2]);
                    acc[r][3] = fmaf(as, w[kk].w, acc[r][3]);
                }
        }
    }
    for (int r = 0; r < 8; ++r) {
        int gr = base + r0 + r;
        if (gr < N_) {
            float4 v = make_float4(acc[r][0], acc[r][1], acc[r][2], acc[r][3]);
            *(float4*)&acc_out[(long)gr * 128 + c0] = v;
        }
    }
}

// ---------------- GraphNorm passes ----------------
__global__ __launch_bounds__(256) void k_pass1(const float* __restrict__ acc, float* cs) {
    __shared__ float sd[256];
    int tid = threadIdx.x;
    int c = tid & 127, half = tid >> 7;
    int base = blockIdx.x * 128 + half * 64;
    float s = 0.f;
    for (int i = 0; i < 64; ++i) {
        int r = base + i;
        if (r < N_) s += gelu_f(acc[(long)r * 128 + c]);
    }
    sd[tid] = s;
    __syncthreads();
    if (tid < 128) atomicAdd(&cs[c], sd[tid] + sd[tid + 128]);
}
__global__ __launch_bounds__(256) void k_pass2(const float* __restrict__ acc, const float* __restrict__ cs,
                                               const float* __restrict__ gsc, float* __restrict__ outb,
                                               float* cq) {
    __shared__ float sd[256];
    int tid = threadIdx.x;
    int c = tid & 127, half = tid >> 7;
    int base = blockIdx.x * 128 + half * 64;
    float mean = cs[c] / 50000.0f;
    float sm = gsc[c] * mean;
    float s = 0.f;
    for (int i = 0; i < 64; ++i) {
        int r = base + i;
        if (r < N_) {
            float g = gelu_f(acc[(long)r * 128 + c]);
            float o = g - sm;
            outb[(long)r * 128 + c] = o;
            s += o * o;
        }
    }
    sd[tid] = s;
    __syncthreads();
    if (tid < 128) atomicAdd(&cq[c], sd[tid] + sd[tid + 128]);
}
__global__ __launch_bounds__(256) void k_pass3(const float* __restrict__ outb, const float* __restrict__ cq,
                                               const float* __restrict__ gw, const float* __restrict__ gb,
                                               float* __restrict__ xs_l) {
    int tid = threadIdx.x;
    int c = tid & 127, half = tid >> 7;
    int base = blockIdx.x * 128 + half * 64;
    float var = cq[c] / 50000.0f;
    float mul = rsqrtf(var + EPS_) * gw[c];
    float add = gb[c];
    for (int i = 0; i < 64; ++i) {
        int r = base + i;
        if (r < N_) xs_l[(long)r * 384 + c] = outb[(long)r * 128 + c] * mul + add;
    }
}

// ---------------- head part 1: [N,384]@Wh1 gelu @Wh2 gelu -> h2 ----------------
__global__ __launch_bounds__(128) void k_head1(const float* __restrict__ xsave,
    const float* __restrict__ Wh1, const float* __restrict__ bh1,
    const float* __restrict__ Wh2, const float* __restrict__ bh2,
    float* __restrict__ h2out) {
    __shared__ float inb[32][388];
    __shared__ float h1b[32][104];
    int tid = threadIdx.x;
    int base = blockIdx.x * 32;
    for (int i = 0; i < 24; ++i) {
        int f4 = i * 128 + tid;
        int r = f4 / 96, c4 = f4 - r * 96;
        float4 v = make_float4(0.f, 0.f, 0.f, 0.f);
        int gr = base + r;
        if (gr < N_) v = *(const float4*)&xsave[(long)gr * 384 + c4 * 4];
        *(float4*)&inb[r][c4 * 4] = v;
    }
    __syncthreads();
    int tx = tid & 31, ty = tid >> 5;
    int c0 = tx * 4, r0 = ty * 8;
    bool valid = (c0 < 100);
    {
        float acc[8][4];
        for (int r = 0; r < 8; ++r)
            for (int j = 0; j < 4; ++j) acc[r][j] = valid ? bh1[c0 + j] : 0.f;
        if (valid) {
            for (int k0 = 0; k0 < 384; k0 += 4) {
                float4 a[8], w[4];
                for (int r = 0; r < 8; ++r) a[r] = *(const float4*)&inb[r0 + r][k0];
                for (int kk = 0; kk < 4; ++kk) w[kk] = *(const float4*)&Wh1[(k0 + kk) * 100 + c0];
                for (int kk = 0; kk < 4; ++kk)
                    for (int r = 0; r < 8; ++r) {
                        float as = (&a[r].x)[kk];
                        acc[r][0] = fmaf(as, w[kk].x, acc[r][0]);
                        acc[r][1] = fmaf(as, w[kk].y, acc[r][1]);
                        acc[r][2] = fmaf(as, w[kk].z, acc[r][2]);
                        acc[r][3] = fmaf(as, w[kk].w, acc[r][3]);
                    }
            }
            for (int r = 0; r < 8; ++r)
                for (int j = 0; j < 4; ++j) h1b[r0 + r][c0 + j] = gelu_f(acc[r][j]);
        }
    }
    __syncthreads();
    {
        float acc[8][4];
        for (int r = 0; r < 8; ++r)
            for (int j = 0; j < 4; ++j) acc[r][j] = valid ? bh2[c0 + j] : 0.f;
        if (valid) {
            for (int k0 = 0; k0 < 100; k0 += 4) {
                float4 a[8], w[4];
                for (int r = 0; r < 8; ++r) a[r] = *(const float4*)&h1b[r0 + r][k0];
                for (int kk = 0; kk < 4; ++kk) w[kk] = *(const float4*)&Wh2[(k0 + kk) * 100 + c0];
                for (int kk = 0; kk < 4; ++kk)
                    for (int r = 0; r < 8; ++r) {
                        float as = (&a[r].x)[kk];
                        acc[r][0] = fmaf(as, w[kk].x, acc[r][0]);
                        acc[r][1] = fmaf(as, w[kk].y, acc[r][1]);
                        acc[r][2] = fmaf(as, w[kk].z, acc[r][2]);
                        acc[r][3] = fmaf(as, w[kk].w, acc[r][3]);
                    }
            }
            for (int r = 0; r < 8; ++r) {
                int gr = base + r0 + r;
                if (gr < N_) {
                    float4 v = make_float4(gelu_f(acc[r][0]), gelu_f(acc[r][1]),
                                           gelu_f(acc[r][2]), gelu_f(acc[r][3]));
                    *(float4*)&h2out[(long)gr * 100 + c0] = v;
                }
            }
        }
    }
}

// ---------------- head part 2 + VQ ----------------
__global__ __launch_bounds__(128) void k_head2(const float* __restrict__ h2,
    const float* __restrict__ xAA,
    const float* __restrict__ Wo1, const float* __restrict__ bo1,
    const float* __restrict__ Wo2, const float* __restrict__ bo2,
    const float* __restrict__ Wo3, const float* __restrict__ bo3,
    const float* __restrict__ cb, float* __restrict__ zq, float* __restrict__ loss) {
    __shared__ __align__(16) float smem[13216];
    float* A  = smem;           // [32][124], also reused as C
    float* B  = smem + 3968;    // [32][104]
    float* XF = smem + 7296;    // [32][36]
    float* CB = smem + 8448;    // [128][36]
    float* CC = smem + 13056;   // [128]
    float* SR = smem + 13184;   // [32]
    int tid = threadIdx.x;
    int base = blockIdx.x * 32;
    for (int i = 0; i < 8; ++i) {
        int f4 = i * 128 + tid;
        int k = f4 >> 3, j4 = f4 & 7;
        float4 v = *(const float4*)&cb[k * 32 + j4 * 4];
        *(float4*)&CB[k * 36 + j4 * 4] = v;
    }
    for (int i = 0; i < 7; ++i) {
        int f4 = i * 128 + tid;
        if (f4 < 800) {
            int r = f4 / 25, c4 = f4 - r * 25;
            float4 v = make_float4(0.f, 0.f, 0.f, 0.f);
            int gr = base + r;
            if (gr < N_) v = *(const float4*)&h2[(long)gr * 100 + c4 * 4];
            *(float4*)&A[r * 124 + c4 * 4] = v;
        }
    }
    for (int i = 0; i < 2; ++i) {
        int f4 = i * 128 + tid;
        if (f4 < 160) {
            int r = f4 / 5, c4 = f4 - r * 5;
            float4 v = make_float4(0.f, 0.f, 0.f, 0.f);
            int gr = base + r;
            if (gr < N_) v = *(const float4*)&xAA[(long)gr * 20 + c4 * 4];
            *(float4*)&A[r * 124 + 100 + c4 * 4] = v;
        }
    }
    __syncthreads();
    if (tid < 128) {
        float s = 0.f;
        for (int j = 0; j < 32; ++j) { float v = CB[tid * 36 + j]; s += v * v; }
        CC[tid] = s;
    }
    int tx = tid & 31, ty = tid >> 5;
    int c0 = tx * 4, r0 = ty * 8;
    bool valid = (c0 < 100);
    {   // GEMM: A[32][120] @ Wo1 -> gelu -> B
        float acc[8][4];
        for (int r = 0; r < 8; ++r)
            for (int j = 0; j < 4; ++j) acc[r][j] = valid ? bo1[c0 + j] : 0.f;
        if (valid) {
            for (int k0 = 0; k0 < 120; k0 += 4) {
                float4 a[8], w[4];
                for (int r = 0; r < 8; ++r) a[r] = *(const float4*)&A[(r0 + r) * 124 + k0];
                for (int kk = 0; kk < 4; ++kk) w[kk] = *(const float4*)&Wo1[(k0 + kk) * 100 + c0];
                for (int kk = 0; kk < 4; ++kk)
                    for (int r = 0; r < 8; ++r) {
                        float as = (&a[r].x)[kk];
                        acc[r][0] = fmaf(as, w[kk].x, acc[r][0]);
                        acc[r][1] = fmaf(as, w[kk].y, acc[r][1]);
                        acc[r][2] = fmaf(as, w[kk].z, acc[r][2]);
                        acc[r][3] = fmaf(as, w[kk].w, acc[r][3]);
                    }
            }
        }
        __syncthreads();
        if (valid)
            for (int r = 0; r < 8; ++r)
                for (int j = 0; j < 4; ++j) B[(r0 + r) * 104 + c0 + j] = gelu_f(acc[r][j]);
    }
    __syncthreads();
    {   // GEMM: B @ Wo2 -> gelu -> C (aliased onto A)
        float acc[8][4];
        for (int r = 0; r < 8; ++r)
            for (int j = 0; j < 4; ++j) acc[r][j] = valid ? bo2[c0 + j] : 0.f;
        if (valid) {
            for (int k0 = 0; k0 < 100; k0 += 4) {
                float4 a[8], w[4];
                for (int r = 0; r < 8; ++r) a[r] = *(const float4*)&B[(r0 + r) * 104 + k0];
                for (int kk = 0; kk < 4; ++kk) w[kk] = *(const float4*)&Wo2[(k0 + kk) * 100 + c0];
                for (int kk = 0; kk < 4; ++kk)
                    for (int r = 0; r < 8; ++r) {
                        float as = (&a[r].x)[kk];
                        acc[r][0] = fmaf(as, w[kk].x, acc[r][0]);
                        acc[r][1] = fmaf(as, w[kk].y, acc[r][1]);
                        acc[r][2] = fmaf(as, w[kk].z, acc[r][2]);
                        acc[r][3] = fmaf(as, w[kk].w, acc[r][3]);
                    }
            }
        }
        __syncthreads();
        if (valid)
            for (int r = 0; r < 8; ++r)
                for (int j = 0; j < 4; ++j) A[(r0 + r) * 124 + c0 + j] = gelu_f(acc[r][j]);
    }
    __syncthreads();
    {   // GEMM: C @ Wo3 -> tanh -> XF
        int c0b = (tid & 7) * 4, rg = tid >> 3;
        int r0b = rg * 2;
        float acc[2][4];
        for (int r = 0; r < 2; ++r)
            for (int j = 0; j < 4; ++j) acc[r][j] = bo3[c0b + j];
        for (int k0 = 0; k0 < 100; k0 += 4) {
            float4 a[2], w[4];
            for (int r = 0; r < 2; ++r) a[r] = *(const float4*)&A[(r0b + r) * 124 + k0];
            for (int kk = 0; kk < 4; ++kk) w[kk] = *(const float4*)&Wo3[(k0 + kk) * 32 + c0b];
            for (int kk = 0; kk < 4; ++kk)
                for (int r = 0; r < 2; ++r) {
                    float as = (&a[r].x)[kk];
                    acc[r][0] = fmaf(as, w[kk].x, acc[r][0]);
                    acc[r][1] = fmaf(as, w[kk].y, acc[r][1]);
                    acc[r][2] = fmaf(as, w[kk].z, acc[r][2]);
                    acc[r][3] = fmaf(as, w[kk].w, acc[r][3]);
                }
        }
        for (int r = 0; r < 2; ++r)
            for (int j = 0; j < 4; ++j) XF[(r0b + r) * 36 + c0b + j] = tanhf(acc[r][j]);
    }
    __syncthreads();
    {   // VQ: 4 threads per node, 32 codes each (interleaved k = kk*4+t4)
        int node = tid >> 2, t4 = tid & 3;
        float4 xv[8];
        for (int j4 = 0; j4 < 8; ++j4) xv[j4] = *(const float4*)&XF[node * 36 + j4 * 4];
        float xx = 0.f;
        for (int j4 = 0; j4 < 8; ++j4)
            xx += xv[j4].x * xv[j4].x + xv[j4].y * xv[j4].y + xv[j4].z * xv[j4].z + xv[j4].w * xv[j4].w;
        float best = 3.4e38f;
        int bidx = 0;
        for (int kk = 0; kk < 32; ++kk) {
            int k = kk * 4 + t4;
            const float* cbr = &CB[k * 36];
            float dot = 0.f;
            for (int j4 = 0; j4 < 8; ++j4) {
                float4 cv = *(const float4*)&cbr[j4 * 4];
                dot += cv.x * xv[j4].x + cv.y * xv[j4].y + cv.z * xv[j4].z + cv.w * xv[j4].w;
            }
            float d = fmaf(-2.0f, dot, xx) + CC[k];
            if (d < best) { best = d; bidx = k; }
        }
        for (int off = 1; off < 4; off <<= 1) {
            float ob = __shfl_xor(best, off);
            int oi = __shfl_xor(bidx, off);
            if (ob < best || (ob == best && oi < bidx)) { best = ob; bidx = oi; }
        }
        int gr = base + node;
        if (t4 == 0) {
            float s = 0.f;
            if (gr < N_) {
                const float* q = &CB[bidx * 36];
                for (int j4 = 0; j4 < 8; ++j4) {
                    float4 qv = *(const float4*)&q[j4 * 4];
                    *(float4*)&zq[(long)gr * 32 + j4 * 4] = qv;
                    float4 xvv = xv[j4];
                    float d0 = qv.x - xvv.x, d1 = qv.y - xvv.y, d2 = qv.z - xvv.z, d3 = qv.w - xvv.w;
                    s += d0 * d0 + d1 * d1 + d2 * d2 + d3 * d3;
                }
            }
            SR[node] = s;
        }
    }
    __syncthreads();
    if (tid == 0) {
        float S = 0.f;
        for (int i = 0; i < 32; ++i) S += SR[i];
        atomicAdd(loss, S);
    }
}

__global__ void k_fin(float* dout, const float* loss) {
    if (threadIdx.x == 0 && blockIdx.x == 0)
        dout[(long)N_ * 32] = 1.25f * (loss[0] / 1600000.0f);
}

extern "C" void kernel_launch(void* const* d_in, const int* in_sizes, int n_in,
                              void* d_out, int out_size, void* d_ws, size_t ws_size,
                              hipStream_t stream) {
    const float* x_res = (const float*)d_in[0];
    const float* x_AA  = (const float*)d_in[1];
    const int*   EI    = (const int*)d_in[2];
    const float* ln_g  = (const float*)d_in[3];
    const float* ln_b  = (const float*)d_in[4];
    const float* W1    = (const float*)d_in[5];
    const float* b1    = (const float*)d_in[6];
    const float* W2    = (const float*)d_in[7];
    const float* b2    = (const float*)d_in[8];
    const float* sWl   = (const float*)d_in[9];
    const float* sWr   = (const float*)d_in[10];
    const float* sb    = (const float*)d_in[11];
    const float* gnw   = (const float*)d_in[12];
    const float* gnb   = (const float*)d_in[13];
    const float* gns   = (const float*)d_in[14];
    const float* Wh1   = (const float*)d_in[15];
    const float* bh1   = (const float*)d_in[16];
    const float* Wh2   = (const float*)d_in[17];
    const float* bh2   = (const float*)d_in[18];
    const float* Wo1   = (const float*)d_in[19];
    const float* bo1   = (const float*)d_in[20];
    const float* Wo2   = (const float*)d_in[21];
    const float* bo2   = (const float*)d_in[22];
    const float* Wo3   = (const float*)d_in[23];
    const float* bo3   = (const float*)d_in[24];
    const float* cbk   = (const float*)d_in[25];
    float* out = (float*)d_out;

    float* ws    = (float*)d_ws;
    float* xsave = ws;                               // N*384
    float* x0    = xsave + (size_t)N_ * 384;         // N*128
    float* agg   = x0 + (size_t)N_ * 128;            // 3*N*128
    float* acc   = agg + (size_t)3 * N_ * 128;       // N*128
    float* wls   = acc + (size_t)N_ * 128;           // 147456
    float* wra   = wls + 147456;                     // 49152
    float* ba    = wra + 49152;                      // 384
    float* cntf  = ba + 384;                         // NG_ (int counts -> float inv, in place)
    float* loss  = cntf + NG_;                       // 1
    float* cs    = loss + 1;                         // 128
    float* cq    = cs + 128;                         // 128
    int*   cnti  = (int*)cntf;
    float* inv   = cntf;
    int*   rp    = (int*)(cq + 128);                 // NG_ ints
    int*   csr   = rp + NG_;                         // T_*E_ ints
    float* outb  = agg;                              // reuse agg slice 0 (dead after gemm)
    float* h2    = agg + (size_t)N_ * 128;           // reuse agg slice 1 (dead after body)

    // zero: counts (NG_ ints) + loss + cs + cq
    hipMemsetAsync(cnti, 0, (NG_ + 257) * sizeof(float), stream);

    k_prep<<<576, 256, 0, stream>>>(sWl, sWr, sb, wls, wra, ba);
    k_count<<<(T_ * E_ + 255) / 256, 256, 0, stream>>>(EI, cnti);
    k_scan<<<1, 1024, 0, stream>>>(cnti, rp);
    k_inv<<<(NG_ + 255) / 256, 256, 0, stream>>>(cnti, inv);
    k_place<<<(T_ * E_ + 255) / 256, 256, 0, stream>>>(EI, rp, csr);
    k_inmlp<<<(N_ + 31) / 32, 256, 0, stream>>>(x_res, ln_g, ln_b, W1, b1, W2, b2, x0);

    for (int l = 0; l < 3; ++l) {
        const float* X = (l == 0) ? x0 : (xsave + (size_t)(l - 1) * 128);
        int ldx = (l == 0) ? 128 : 384;
        k_gather<<<NG_ / 8, 256, 0, stream>>>(rp, csr, inv, X, ldx, agg);
        k_gemm_body<<<(N_ + 63) / 64, 256, 0, stream>>>(X, ldx, agg,
            wls + (size_t)l * 3 * 16384, wra + (size_t)l * 16384, ba + l * 128,
            acc, cs, cq);
        k_pass1<<<(N_ + 127) / 128, 256, 0, stream>>>(acc, cs);
        k_pass2<<<(N_ + 127) / 128, 256, 0, stream>>>(acc, cs, gns + l * 128, outb, cq);
        k_pass3<<<(N_ + 127) / 128, 256, 0, stream>>>(outb, cq, gnw + l * 128, gnb + l * 128,
                                                      xsave + (size_t)l * 128);
    }
    k_head1<<<(N_ + 31) / 32, 128, 0, stream>>>(xsave, Wh1, bh1, Wh2, bh2, h2);
    k_head2<<<(N_ + 31) / 32, 128, 0, stream>>>(h2, x_AA, Wo1, bo1, Wo2, bo2, Wo3, bo3,
                                                cbk, out, loss);
    k_fin<<<1, 64, 0, stream>>>(out, loss);
}

// Round 3
// 1658.506 us; speedup vs baseline: 7.9239x; 1.2520x over previous
//
#include <hip/hip_runtime.h>

#define N_ 50000
#define E_ 800000
#define T_ 3
#define NG_ (T_ * N_)   // 150000 (type,dst) groups
#define EPS_ 1e-5f

__device__ __forceinline__ float gelu_f(float x) {
    return 0.5f * x * (1.0f + erff(x * 0.70710678118654752440f));
}

// ---------------- weight prep: Wl/3, mean(Wr), mean(b) ----------------
__global__ void k_prep(const float* __restrict__ Wl, const float* __restrict__ Wr,
                       const float* __restrict__ b, float* wls, float* wra, float* ba) {
    int i = blockIdx.x * 256 + threadIdx.x;
    const float third = 1.0f / 3.0f;
    if (i < 9 * 128 * 128) wls[i] = Wl[i] * third;
    if (i < 3 * 128 * 128) {
        int l = i >> 14, rem = i & 16383;
        const float* p = Wr + l * 3 * 16384 + rem;
        wra[i] = (p[0] + p[16384] + p[32768]) * third;
    }
    if (i < 3 * 128) {
        int l = i >> 7, c = i & 127;
        const float* p = b + l * 3 * 128 + c;
        ba[i] = (p[0] + p[128] + p[256]) * third;
    }
}

// ---------------- per-(type,dst) degree counts (int) ----------------
__global__ void k_count(const int* __restrict__ EI, int* cnt) {
    int i = blockIdx.x * 256 + threadIdx.x;
    if (i >= T_ * E_) return;
    int t = i / E_, e = i - t * E_;
    int d = EI[(t * 2 + 1) * E_ + e];
    atomicAdd(&cnt[t * N_ + d], 1);
}

// ---------------- segment allocation (no prefix scan): contiguous per group ----------------
__global__ void k_alloc(const int* __restrict__ cnt, int* __restrict__ cursor,
                        int* __restrict__ rpA, int* __restrict__ rpB, float* __restrict__ inv) {
    int i = blockIdx.x * 256 + threadIdx.x;
    if (i >= NG_) return;
    int c = cnt[i];
    inv[i] = 1.0f / (float)(c > 0 ? c : 1);
    int s = atomicAdd(cursor, c);
    rpA[i] = s;
    rpB[i] = s;
}

// ---------------- CSR placement: rpB is a per-group running cursor ----------------
__global__ void k_place(const int* __restrict__ EI, int* __restrict__ rpB, int* __restrict__ csr) {
    int i = blockIdx.x * 256 + threadIdx.x;
    if (i >= T_ * E_) return;
    int t = i / E_, e = i - t * E_;
    int s = EI[(t * 2) * E_ + e];
    int d = EI[(t * 2 + 1) * E_ + e];
    int pos = atomicAdd(&rpB[t * N_ + d], 1);
    csr[pos] = s;
}

// ---------------- input LN + MLP (64 -> 256 -> 128) ----------------
__global__ __launch_bounds__(256) void k_inmlp(
    const float* __restrict__ xres, const float* __restrict__ gam, const float* __restrict__ bet,
    const float* __restrict__ W1, const float* __restrict__ b1,
    const float* __restrict__ W2, const float* __restrict__ b2, float* __restrict__ x0) {
    __shared__ float xr[32][68];
    __shared__ float h1[32][260];
    int tid = threadIdx.x;
    int base = blockIdx.x * 32;
    for (int i = 0; i < 2; ++i) {
        int f4 = i * 256 + tid;
        int r = f4 >> 4, c4 = f4 & 15;
        float4 v = make_float4(0.f, 0.f, 0.f, 0.f);
        int gr = base + r;
        if (gr < N_) v = *(const float4*)&xres[gr * 64 + c4 * 4];
        *(float4*)&xr[r][c4 * 4] = v;
    }
    __syncthreads();
    if (tid < 32) {
        int r = tid;
        float s = 0.f;
        for (int k = 0; k < 64; ++k) s += xr[r][k];
        float mu = s * (1.0f / 64.0f);
        float v = 0.f;
        for (int k = 0; k < 64; ++k) { float d = xr[r][k] - mu; v += d * d; }
        float rs = rsqrtf(v * (1.0f / 64.0f) + EPS_);
        for (int k = 0; k < 64; ++k)
            xr[r][k] = (xr[r][k] - mu) * rs * gam[k] + bet[k];
    }
    __syncthreads();
    {   // GEMM1 [32x64]@[64x256] -> gelu -> h1
        int tx = tid & 63, ty = tid >> 6;
        int c0 = tx * 4, r0 = ty * 8;
        float acc[8][4];
        for (int r = 0; r < 8; ++r)
            for (int j = 0; j < 4; ++j) acc[r][j] = b1[c0 + j];
        for (int k0 = 0; k0 < 64; k0 += 4) {
            float4 a[8], w[4];
            for (int r = 0; r < 8; ++r) a[r] = *(const float4*)&xr[r0 + r][k0];
            for (int kk = 0; kk < 4; ++kk) w[kk] = *(const float4*)&W1[(k0 + kk) * 256 + c0];
            for (int kk = 0; kk < 4; ++kk)
                for (int r = 0; r < 8; ++r) {
                    float as = (&a[r].x)[kk];
                    acc[r][0] = fmaf(as, w[kk].x, acc[r][0]);
                    acc[r][1] = fmaf(as, w[kk].y, acc[r][1]);
                    acc[r][2] = fmaf(as, w[kk].z, acc[r][2]);
                    acc[r][3] = fmaf(as, w[kk].w, acc[r][3]);
                }
        }
        for (int r = 0; r < 8; ++r)
            for (int j = 0; j < 4; ++j) h1[r0 + r][c0 + j] = gelu_f(acc[r][j]);
    }
    __syncthreads();
    {   // GEMM2 [32x256]@[256x128] -> gelu -> x0
        int tx = tid & 31, ty = tid >> 5;
        int c0 = tx * 4, r0 = ty * 4;
        float acc[4][4];
        for (int r = 0; r < 4; ++r)
            for (int j = 0; j < 4; ++j) acc[r][j] = b2[c0 + j];
        for (int k0 = 0; k0 < 256; k0 += 4) {
            float4 a[4], w[4];
            for (int r = 0; r < 4; ++r) a[r] = *(const float4*)&h1[r0 + r][k0];
            for (int kk = 0; kk < 4; ++kk) w[kk] = *(const float4*)&W2[(k0 + kk) * 128 + c0];
            for (int kk = 0; kk < 4; ++kk)
                for (int r = 0; r < 4; ++r) {
                    float as = (&a[r].x)[kk];
                    acc[r][0] = fmaf(as, w[kk].x, acc[r][0]);
                    acc[r][1] = fmaf(as, w[kk].y, acc[r][1]);
                    acc[r][2] = fmaf(as, w[kk].z, acc[r][2]);
                    acc[r][3] = fmaf(as, w[kk].w, acc[r][3]);
                }
        }
        for (int r = 0; r < 4; ++r) {
            int gr = base + r0 + r;
            if (gr < N_) {
                float4 v = make_float4(gelu_f(acc[r][0]), gelu_f(acc[r][1]),
                                       gelu_f(acc[r][2]), gelu_f(acc[r][3]));
                *(float4*)&x0[(long)gr * 128 + c0] = v;
            }
        }
    }
}

// ---------------- CSR gather: agg[g] = inv * sum_{src} X[src]; 1 wave = 1 group, 2 edges/iter ----
__global__ __launch_bounds__(256) void k_gather(
    const int* __restrict__ rpA, const int* __restrict__ cnt, const int* __restrict__ csr,
    const float* __restrict__ inv, const float* __restrict__ X, int ldx, float* __restrict__ agg) {
    int tid = threadIdx.x;
    int g = blockIdx.x * 4 + (tid >> 6);
    if (g >= NG_) return;
    int lane = tid & 63;
    int half = lane >> 5;
    int f = (lane & 31) * 4;
    int start = rpA[g];
    int end = start + cnt[g];
    float4 s = make_float4(0.f, 0.f, 0.f, 0.f);
    for (int e = start + half; e < end; e += 2) {
        int sn = csr[e];
        const float4 v = *(const float4*)&X[(long)sn * ldx + f];
        s.x += v.x; s.y += v.y; s.z += v.z; s.w += v.w;
    }
    s.x += __shfl_xor(s.x, 32);
    s.y += __shfl_xor(s.y, 32);
    s.z += __shfl_xor(s.z, 32);
    s.w += __shfl_xor(s.w, 32);
    if (half == 0) {
        float iv = inv[g];
        float4 o = make_float4(s.x * iv, s.y * iv, s.z * iv, s.w * iv);
        *(float4*)&agg[(long)g * 128 + f] = o;
    }
}

// ---- body GEMM: g_out = gelu(sum_t agg_t@(Wl_t/3) + x@Wr_avg + b_avg); cs_l += colsum(g) ----
__global__ __launch_bounds__(256) void k_gemm_body(
    const float* __restrict__ X, int ldx, const float* __restrict__ agg,
    const float* __restrict__ wls_l, const float* __restrict__ wra_l, const float* __restrict__ ba_l,
    float* __restrict__ g_out, float* __restrict__ cs_l) {
    __shared__ float xs[64][132];
    __shared__ float sd[8][128];
    int tid = threadIdx.x;
    int base = blockIdx.x * 64;
    int tx = tid & 31, ty = tid >> 5;
    int c0 = tx * 4, r0 = ty * 8;
    float acc[8][4];
    for (int r = 0; r < 8; ++r)
        for (int j = 0; j < 4; ++j) acc[r][j] = ba_l[c0 + j];
    for (int seg = 0; seg < 4; ++seg) {
        const float* src; long ld;
        if (seg < 3) { src = agg + ((long)seg * N_ + base) * 128; ld = 128; }
        else         { src = X + (long)base * ldx; ld = ldx; }
        __syncthreads();
        for (int i = 0; i < 8; ++i) {
            int f4 = i * 256 + tid;
            int r = f4 >> 5, c4 = f4 & 31;
            float4 v = make_float4(0.f, 0.f, 0.f, 0.f);
            if (base + r < N_) v = *(const float4*)&src[(long)r * ld + c4 * 4];
            *(float4*)&xs[r][c4 * 4] = v;
        }
        __syncthreads();
        const float* W = (seg < 3) ? (wls_l + seg * 16384) : wra_l;
        for (int k0 = 0; k0 < 128; k0 += 4) {
            float4 a[8], w[4];
            for (int r = 0; r < 8; ++r) a[r] = *(const float4*)&xs[r0 + r][k0];
            for (int kk = 0; kk < 4; ++kk) w[kk] = *(const float4*)&W[(k0 + kk) * 128 + c0];
            for (int kk = 0; kk < 4; ++kk)
                for (int r = 0; r < 8; ++r) {
                    float as = (&a[r].x)[kk];
                    acc[r][0] = fmaf(as, w[kk].x, acc[r][0]);
                    acc[r][1] = fmaf(as, w[kk].y, acc[r][1]);
                    acc[r][2] = fmaf(as, w[kk].z, acc[r][2]);
                    acc[r][3] = fmaf(as, w[kk].w, acc[r][3]);
                }
        }
    }
    // epilogue: gelu, store, per-block column sums
    float csum[4] = {0.f, 0.f, 0.f, 0.f};
    for (int r = 0; r < 8; ++r) {
        int gr = base + r0 + r;
        if (gr < N_) {
            float g0 = gelu_f(acc[r][0]), g1 = gelu_f(acc[r][1]);
            float g2 = gelu_f(acc[r][2]), g3 = gelu_f(acc[r][3]);
            *(float4*)&g_out[(long)gr * 128 + c0] = make_float4(g0, g1, g2, g3);
            csum[0] += g0; csum[1] += g1; csum[2] += g2; csum[3] += g3;
        }
    }
    *(float4*)&sd[ty][c0] = make_float4(csum[0], csum[1], csum[2], csum[3]);
    __syncthreads();
    if (tid < 128) {
        float t = 0.f;
        for (int i = 0; i < 8; ++i) t += sd[i][tid];
        atomicAdd(&cs_l[tid], t);
    }
}

// ---------------- GraphNorm: var accumulate (read-only) ----------------
__global__ __launch_bounds__(256) void k_pass2(const float* __restrict__ g,
                                               const float* __restrict__ cs_l,
                                               const float* __restrict__ gsc, float* __restrict__ cq_l) {
    __shared__ float sd[256];
    int tid = threadIdx.x;
    int c = tid & 127, half = tid >> 7;
    int base = blockIdx.x * 128 + half * 64;
    float sm = gsc[c] * (cs_l[c] / 50000.0f);
    float s = 0.f;
    for (int i = 0; i < 64; ++i) {
        int r = base + i;
        if (r < N_) { float o = g[(long)r * 128 + c] - sm; s += o * o; }
    }
    sd[tid] = s;
    __syncthreads();
    if (tid < 128) atomicAdd(&cq_l[c], sd[tid] + sd[tid + 128]);
}
// ---------------- GraphNorm: final scale -> xsave ----------------
__global__ __launch_bounds__(256) void k_pass3(const float* __restrict__ g,
                                               const float* __restrict__ cs_l, const float* __restrict__ cq_l,
                                               const float* __restrict__ gsc,
                                               const float* __restrict__ gw, const float* __restrict__ gb,
                                               float* __restrict__ xs_l) {
    int tid = threadIdx.x;
    int c = tid & 127, half = tid >> 7;
    int base = blockIdx.x * 128 + half * 64;
    float sm = gsc[c] * (cs_l[c] / 50000.0f);
    float var = cq_l[c] / 50000.0f;
    float mul = rsqrtf(var + EPS_) * gw[c];
    float add = gb[c];
    for (int i = 0; i < 64; ++i) {
        int r = base + i;
        if (r < N_) xs_l[(long)r * 384 + c] = (g[(long)r * 128 + c] - sm) * mul + add;
    }
}

// ---------------- head part 1: [N,384]@Wh1 gelu @Wh2 gelu -> h2 (K-tiled, 64 rows) ----------------
__global__ __launch_bounds__(256) void k_head1(const float* __restrict__ xsave,
    const float* __restrict__ Wh1, const float* __restrict__ bh1,
    const float* __restrict__ Wh2, const float* __restrict__ bh2,
    float* __restrict__ h2out) {
    __shared__ float at[64][68];
    __shared__ float h1b[64][104];
    int tid = threadIdx.x;
    int base = blockIdx.x * 64;
    int tx = tid & 31, ty = tid >> 5;
    int c0 = tx * 4, r0 = ty * 8;
    bool valid = (c0 < 100);
    float acc[8][4];
    for (int r = 0; r < 8; ++r)
        for (int j = 0; j < 4; ++j) acc[r][j] = valid ? bh1[c0 + j] : 0.f;
    for (int kt = 0; kt < 6; ++kt) {
        __syncthreads();
        for (int i = 0; i < 4; ++i) {
            int f4 = i * 256 + tid;
            int r = f4 >> 4, c4 = f4 & 15;
            float4 v = make_float4(0.f, 0.f, 0.f, 0.f);
            int gr = base + r;
            if (gr < N_) v = *(const float4*)&xsave[(long)gr * 384 + kt * 64 + c4 * 4];
            *(float4*)&at[r][c4 * 4] = v;
        }
        __syncthreads();
        if (valid) {
            for (int k0 = 0; k0 < 64; k0 += 4) {
                float4 a[8], w[4];
                for (int r = 0; r < 8; ++r) a[r] = *(const float4*)&at[r0 + r][k0];
                for (int kk = 0; kk < 4; ++kk) w[kk] = *(const float4*)&Wh1[(kt * 64 + k0 + kk) * 100 + c0];
                for (int kk = 0; kk < 4; ++kk)
                    for (int r = 0; r < 8; ++r) {
                        float as = (&a[r].x)[kk];
                        acc[r][0] = fmaf(as, w[kk].x, acc[r][0]);
                        acc[r][1] = fmaf(as, w[kk].y, acc[r][1]);
                        acc[r][2] = fmaf(as, w[kk].z, acc[r][2]);
                        acc[r][3] = fmaf(as, w[kk].w, acc[r][3]);
                    }
            }
        }
    }
    __syncthreads();
    if (valid)
        for (int r = 0; r < 8; ++r)
            for (int j = 0; j < 4; ++j) h1b[r0 + r][c0 + j] = gelu_f(acc[r][j]);
    __syncthreads();
    {
        float acc2[8][4];
        for (int r = 0; r < 8; ++r)
            for (int j = 0; j < 4; ++j) acc2[r][j] = valid ? bh2[c0 + j] : 0.f;
        if (valid) {
            for (int k0 = 0; k0 < 100; k0 += 4) {
                float4 a[8], w[4];
                for (int r = 0; r < 8; ++r) a[r] = *(const float4*)&h1b[r0 + r][k0];
                for (int kk = 0; kk < 4; ++kk) w[kk] = *(const float4*)&Wh2[(k0 + kk) * 100 + c0];
                for (int kk = 0; kk < 4; ++kk)
                    for (int r = 0; r < 8; ++r) {
                        float as = (&a[r].x)[kk];
                        acc2[r][0] = fmaf(as, w[kk].x, acc2[r][0]);
                        acc2[r][1] = fmaf(as, w[kk].y, acc2[r][1]);
                        acc2[r][2] = fmaf(as, w[kk].z, acc2[r][2]);
                        acc2[r][3] = fmaf(as, w[kk].w, acc2[r][3]);
                    }
            }
            for (int r = 0; r < 8; ++r) {
                int gr = base + r0 + r;
                if (gr < N_) {
                    float4 v = make_float4(gelu_f(acc2[r][0]), gelu_f(acc2[r][1]),
                                           gelu_f(acc2[r][2]), gelu_f(acc2[r][3]));
                    *(float4*)&h2out[(long)gr * 100 + c0] = v;
                }
            }
        }
    }
}

// ---------------- head part 2 + VQ ----------------
__global__ __launch_bounds__(128) void k_head2(const float* __restrict__ h2,
    const float* __restrict__ xAA,
    const float* __restrict__ Wo1, const float* __restrict__ bo1,
    const float* __restrict__ Wo2, const float* __restrict__ bo2,
    const float* __restrict__ Wo3, const float* __restrict__ bo3,
    const float* __restrict__ cb, float* __restrict__ zq, float* __restrict__ loss) {
    __shared__ __align__(16) float smem[13216];
    float* A  = smem;           // [32][124], also reused as C
    float* B  = smem + 3968;    // [32][104]
    float* XF = smem + 7296;    // [32][36]
    float* CB = smem + 8448;    // [128][36]
    float* CC = smem + 13056;   // [128]
    float* SR = smem + 13184;   // [32]
    int tid = threadIdx.x;
    int base = blockIdx.x * 32;
    for (int i = 0; i < 8; ++i) {
        int f4 = i * 128 + tid;
        int k = f4 >> 3, j4 = f4 & 7;
        float4 v = *(const float4*)&cb[k * 32 + j4 * 4];
        *(float4*)&CB[k * 36 + j4 * 4] = v;
    }
    for (int i = 0; i < 7; ++i) {
        int f4 = i * 128 + tid;
        if (f4 < 800) {
            int r = f4 / 25, c4 = f4 - r * 25;
            float4 v = make_float4(0.f, 0.f, 0.f, 0.f);
            int gr = base + r;
            if (gr < N_) v = *(const float4*)&h2[(long)gr * 100 + c4 * 4];
            *(float4*)&A[r * 124 + c4 * 4] = v;
        }
    }
    for (int i = 0; i < 2; ++i) {
        int f4 = i * 128 + tid;
        if (f4 < 160) {
            int r = f4 / 5, c4 = f4 - r * 5;
            float4 v = make_float4(0.f, 0.f, 0.f, 0.f);
            int gr = base + r;
            if (gr < N_) v = *(const float4*)&xAA[(long)gr * 20 + c4 * 4];
            *(float4*)&A[r * 124 + 100 + c4 * 4] = v;
        }
    }
    __syncthreads();
    if (tid < 128) {
        float s = 0.f;
        for (int j = 0; j < 32; ++j) { float v = CB[tid * 36 + j]; s += v * v; }
        CC[tid] = s;
    }
    int tx = tid & 31, ty = tid >> 5;
    int c0 = tx * 4, r0 = ty * 8;
    bool valid = (c0 < 100);
    {   // GEMM: A[32][120] @ Wo1 -> gelu -> B
        float acc[8][4];
        for (int r = 0; r < 8; ++r)
            for (int j = 0; j < 4; ++j) acc[r][j] = valid ? bo1[c0 + j] : 0.f;
        if (valid) {
            for (int k0 = 0; k0 < 120; k0 += 4) {
                float4 a[8], w[4];
                for (int r = 0; r < 8; ++r) a[r] = *(const float4*)&A[(r0 + r) * 124 + k0];
                for (int kk = 0; kk < 4; ++kk) w[kk] = *(const float4*)&Wo1[(k0 + kk) * 100 + c0];
                for (int kk = 0; kk < 4; ++kk)
                    for (int r = 0; r < 8; ++r) {
                        float as = (&a[r].x)[kk];
                        acc[r][0] = fmaf(as, w[kk].x, acc[r][0]);
                        acc[r][1] = fmaf(as, w[kk].y, acc[r][1]);
                        acc[r][2] = fmaf(as, w[kk].z, acc[r][2]);
                        acc[r][3] = fmaf(as, w[kk].w, acc[r][3]);
                    }
            }
        }
        __syncthreads();
        if (valid)
            for (int r = 0; r < 8; ++r)
                for (int j = 0; j < 4; ++j) B[(r0 + r) * 104 + c0 + j] = gelu_f(acc[r][j]);
    }
    __syncthreads();
    {   // GEMM: B @ Wo2 -> gelu -> C (aliased onto A)
        float acc[8][4];
        for (int r = 0; r < 8; ++r)
            for (int j = 0; j < 4; ++j) acc[r][j] = valid ? bo2[c0 + j] : 0.f;
        if (valid) {
            for (int k0 = 0; k0 < 100; k0 += 4) {
                float4 a[8], w[4];
                for (int r = 0; r < 8; ++r) a[r] = *(const float4*)&B[(r0 + r) * 104 + k0];
                for (int kk = 0; kk < 4; ++kk) w[kk] = *(const float4*)&Wo2[(k0 + kk) * 100 + c0];
                for (int kk = 0; kk < 4; ++kk)
                    for (int r = 0; r < 8; ++r) {
                        float as = (&a[r].x)[kk];
                        acc[r][0] = fmaf(as, w[kk].x, acc[r][0]);
                        acc[r][1] = fmaf(as, w[kk].y, acc[r][1]);
                        acc[r][2] = fmaf(as, w[kk].z, acc[r][2]);
                        acc[r][3] = fmaf(as, w[kk].w, acc[r][3]);
                    }
            }
        }
        __syncthreads();
        if (valid)
            for (int r = 0; r < 8; ++r)
                for (int j = 0; j < 4; ++j) A[(r0 + r) * 124 + c0 + j] = gelu_f(acc[r][j]);
    }
    __syncthreads();
    {   // GEMM: C @ Wo3 -> tanh -> XF
        int c0b = (tid & 7) * 4, rg = tid >> 3;
        int r0b = rg * 2;
        float acc[2][4];
        for (int r = 0; r < 2; ++r)
            for (int j = 0; j < 4; ++j) acc[r][j] = bo3[c0b + j];
        for (int k0 = 0; k0 < 100; k0 += 4) {
            float4 a[2], w[4];
            for (int r = 0; r < 2; ++r) a[r] = *(const float4*)&A[(r0b + r) * 124 + k0];
            for (int kk = 0; kk < 4; ++kk) w[kk] = *(const float4*)&Wo3[(k0 + kk) * 32 + c0b];
            for (int kk = 0; kk < 4; ++kk)
                for (int r = 0; r < 2; ++r) {
                    float as = (&a[r].x)[kk];
                    acc[r][0] = fmaf(as, w[kk].x, acc[r][0]);
                    acc[r][1] = fmaf(as, w[kk].y, acc[r][1]);
                    acc[r][2] = fmaf(as, w[kk].z, acc[r][2]);
                    acc[r][3] = fmaf(as, w[kk].w, acc[r][3]);
                }
        }
        for (int r = 0; r < 2; ++r)
            for (int j = 0; j < 4; ++j) XF[(r0b + r) * 36 + c0b + j] = tanhf(acc[r][j]);
    }
    __syncthreads();
    {   // VQ: 4 threads per node, 32 codes each (interleaved k = kk*4+t4)
        int node = tid >> 2, t4 = tid & 3;
        float4 xv[8];
        for (int j4 = 0; j4 < 8; ++j4) xv[j4] = *(const float4*)&XF[node * 36 + j4 * 4];
        float xx = 0.f;
        for (int j4 = 0; j4 < 8; ++j4)
            xx += xv[j4].x * xv[j4].x + xv[j4].y * xv[j4].y + xv[j4].z * xv[j4].z + xv[j4].w * xv[j4].w;
        float best = 3.4e38f;
        int bidx = 0;
        for (int kk = 0; kk < 32; ++kk) {
            int k = kk * 4 + t4;
            const float* cbr = &CB[k * 36];
            float dot = 0.f;
            for (int j4 = 0; j4 < 8; ++j4) {
                float4 cv = *(const float4*)&cbr[j4 * 4];
                dot += cv.x * xv[j4].x + cv.y * xv[j4].y + cv.z * xv[j4].z + cv.w * xv[j4].w;
            }
            float d = fmaf(-2.0f, dot, xx) + CC[k];
            if (d < best) { best = d; bidx = k; }
        }
        for (int off = 1; off < 4; off <<= 1) {
            float ob = __shfl_xor(best, off);
            int oi = __shfl_xor(bidx, off);
            if (ob < best || (ob == best && oi < bidx)) { best = ob; bidx = oi; }
        }
        int gr = base + node;
        if (t4 == 0) {
            float s = 0.f;
            if (gr < N_) {
                const float* q = &CB[bidx * 36];
                for (int j4 = 0; j4 < 8; ++j4) {
                    float4 qv = *(const float4*)&q[j4 * 4];
                    *(float4*)&zq[(long)gr * 32 + j4 * 4] = qv;
                    float4 xvv = xv[j4];
                    float d0 = qv.x - xvv.x, d1 = qv.y - xvv.y, d2 = qv.z - xvv.z, d3 = qv.w - xvv.w;
                    s += d0 * d0 + d1 * d1 + d2 * d2 + d3 * d3;
                }
            }
            SR[node] = s;
        }
    }
    __syncthreads();
    if (tid == 0) {
        float S = 0.f;
        for (int i = 0; i < 32; ++i) S += SR[i];
        atomicAdd(loss, S);
    }
}

__global__ void k_fin(float* dout, const float* loss) {
    if (threadIdx.x == 0 && blockIdx.x == 0)
        dout[(long)N_ * 32] = 1.25f * (loss[0] / 1600000.0f);
}

extern "C" void kernel_launch(void* const* d_in, const int* in_sizes, int n_in,
                              void* d_out, int out_size, void* d_ws, size_t ws_size,
                              hipStream_t stream) {
    const float* x_res = (const float*)d_in[0];
    const float* x_AA  = (const float*)d_in[1];
    const int*   EI    = (const int*)d_in[2];
    const float* ln_g  = (const float*)d_in[3];
    const float* ln_b  = (const float*)d_in[4];
    const float* W1    = (const float*)d_in[5];
    const float* b1    = (const float*)d_in[6];
    const float* W2    = (const float*)d_in[7];
    const float* b2    = (const float*)d_in[8];
    const float* sWl   = (const float*)d_in[9];
    const float* sWr   = (const float*)d_in[10];
    const float* sb    = (const float*)d_in[11];
    const float* gnw   = (const float*)d_in[12];
    const float* gnb   = (const float*)d_in[13];
    const float* gns   = (const float*)d_in[14];
    const float* Wh1   = (const float*)d_in[15];
    const float* bh1   = (const float*)d_in[16];
    const float* Wh2   = (const float*)d_in[17];
    const float* bh2   = (const float*)d_in[18];
    const float* Wo1   = (const float*)d_in[19];
    const float* bo1   = (const float*)d_in[20];
    const float* Wo2   = (const float*)d_in[21];
    const float* bo2   = (const float*)d_in[22];
    const float* Wo3   = (const float*)d_in[23];
    const float* bo3   = (const float*)d_in[24];
    const float* cbk   = (const float*)d_in[25];
    float* out = (float*)d_out;

    float* ws    = (float*)d_ws;
    float* xsave = ws;                               // N*384
    float* x0    = xsave + (size_t)N_ * 384;         // N*128
    float* agg   = x0 + (size_t)N_ * 128;            // 3*N*128
    float* gbuf  = agg + (size_t)3 * N_ * 128;       // N*128 (gelu of conv out)
    float* wls   = gbuf + (size_t)N_ * 128;          // 147456
    float* wra   = wls + 147456;                     // 49152
    float* ba    = wra + 49152;                      // 384
    // zero-init region: [cnt NG][cursor 1][loss 1][cs 3*128][cq 3*128]
    int*   cnti  = (int*)(ba + 384);                 // NG_ ints
    int*   cursor= cnti + NG_;                       // 1
    float* loss  = (float*)(cursor + 1);             // 1
    float* cs    = loss + 1;                         // 3*128
    float* cq    = cs + 384;                         // 3*128
    float* inv   = cq + 384;                         // NG_
    int*   rpA   = (int*)(inv + NG_);                // NG_
    int*   rpB   = rpA + NG_;                        // NG_
    int*   csr   = rpB + NG_;                        // T_*E_
    float* h2    = agg + (size_t)N_ * 128;           // reuse agg slice 1 (dead after body)

    hipMemsetAsync(cnti, 0, (NG_ + 2 + 768) * sizeof(int), stream);

    k_prep<<<576, 256, 0, stream>>>(sWl, sWr, sb, wls, wra, ba);
    k_count<<<(T_ * E_ + 255) / 256, 256, 0, stream>>>(EI, cnti);
    k_alloc<<<(NG_ + 255) / 256, 256, 0, stream>>>(cnti, cursor, rpA, rpB, inv);
    k_place<<<(T_ * E_ + 255) / 256, 256, 0, stream>>>(EI, rpB, csr);
    k_inmlp<<<(N_ + 31) / 32, 256, 0, stream>>>(x_res, ln_g, ln_b, W1, b1, W2, b2, x0);

    for (int l = 0; l < 3; ++l) {
        const float* X = (l == 0) ? x0 : (xsave + (size_t)(l - 1) * 128);
        int ldx = (l == 0) ? 128 : 384;
        k_gather<<<NG_ / 4, 256, 0, stream>>>(rpA, cnti, csr, inv, X, ldx, agg);
        k_gemm_body<<<(N_ + 63) / 64, 256, 0, stream>>>(X, ldx, agg,
            wls + (size_t)l * 3 * 16384, wra + (size_t)l * 16384, ba + l * 128,
            gbuf, cs + l * 128);
        k_pass2<<<(N_ + 127) / 128, 256, 0, stream>>>(gbuf, cs + l * 128, gns + l * 128, cq + l * 128);
        k_pass3<<<(N_ + 127) / 128, 256, 0, stream>>>(gbuf, cs + l * 128, cq + l * 128,
                                                      gns + l * 128, gnw + l * 128, gnb + l * 128,
                                                      xsave + (size_t)l * 128);
    }
    k_head1<<<(N_ + 63) / 64, 256, 0, stream>>>(xsave, Wh1, bh1, Wh2, bh2, h2);
    k_head2<<<(N_ + 31) / 32, 128, 0, stream>>>(h2, x_AA, Wo1, bo1, Wo2, bo2, Wo3, bo3,
                                                cbk, out, loss);
    k_fin<<<1, 64, 0, stream>>>(out, loss);
}

// Round 4
// 1549.154 us; speedup vs baseline: 8.4833x; 1.0706x over previous
//
#include <hip/hip_runtime.h>

#define N_ 50000
#define E_ 800000
#define T_ 3
#define NG_ (T_ * N_)   // 150000 (type,dst) groups
#define EPS_ 1e-5f

__device__ __forceinline__ float gelu_f(float x) {
    return 0.5f * x * (1.0f + erff(x * 0.70710678118654752440f));
}

// ---------------- weight prep: Wl/3, mean(Wr), mean(b) ----------------
__global__ void k_prep(const float* __restrict__ Wl, const float* __restrict__ Wr,
                       const float* __restrict__ b, float* wls, float* wra, float* ba) {
    int i = blockIdx.x * 256 + threadIdx.x;
    const float third = 1.0f / 3.0f;
    if (i < 9 * 128 * 128) wls[i] = Wl[i] * third;
    if (i < 3 * 128 * 128) {
        int l = i >> 14, rem = i & 16383;
        const float* p = Wr + l * 3 * 16384 + rem;
        wra[i] = (p[0] + p[16384] + p[32768]) * third;
    }
    if (i < 3 * 128) {
        int l = i >> 7, c = i & 127;
        const float* p = b + l * 3 * 128 + c;
        ba[i] = (p[0] + p[128] + p[256]) * third;
    }
}

// ---------------- linked-list build: head[g] -> chain of global edge ids ----------------
__global__ void k_link(const int* __restrict__ EI, int* __restrict__ head, int* __restrict__ nxt) {
    int i = blockIdx.x * 256 + threadIdx.x;
    if (i >= T_ * E_) return;
    int t = i / E_, e = i - t * E_;
    int d = EI[(t * 2 + 1) * E_ + e];
    nxt[i] = atomicExch(&head[t * N_ + d], i);
}

// ---- compact lists -> csr segments; cnt/inv; wave-scanned cursor allocation ----
__global__ __launch_bounds__(256) void k_compact(
    const int* __restrict__ EI, const int* __restrict__ head, const int* __restrict__ nxt,
    int* __restrict__ cursor, int* __restrict__ cnt, int* __restrict__ rpA,
    float* __restrict__ inv, int* __restrict__ csr) {
    int tid = threadIdx.x;
    int g = blockIdx.x * 256 + tid;
    bool ok = (g < NG_);
    int lane = tid & 63;
    int c = 0;
    int h = -1;
    if (ok) {
        h = head[g];
        int e = h;
        while (e >= 0) { c++; e = nxt[e]; }
        cnt[g] = c;
        inv[g] = 1.0f / (float)(c > 0 ? c : 1);
    }
    // wave-inclusive prefix scan of c
    int x = c;
    for (int off = 1; off < 64; off <<= 1) {
        int y = __shfl_up(x, off);
        if (lane >= off) x += y;
    }
    int total = __shfl(x, 63);
    int base = 0;
    if (lane == 63 && total > 0) base = atomicAdd(cursor, total);
    base = __shfl(base, 63);
    if (ok) {
        int pos = base + x - c;
        rpA[g] = pos;
        int e = h;
        while (e >= 0) {
            int t = e / E_, idx = e - t * E_;
            csr[pos++] = EI[(t * 2) * E_ + idx];
            e = nxt[e];
        }
    }
}

// ---------------- input LN + MLP (64 -> 256 -> 128) ----------------
__global__ __launch_bounds__(256) void k_inmlp(
    const float* __restrict__ xres, const float* __restrict__ gam, const float* __restrict__ bet,
    const float* __restrict__ W1, const float* __restrict__ b1,
    const float* __restrict__ W2, const float* __restrict__ b2, float* __restrict__ x0) {
    __shared__ float xr[32][68];
    __shared__ float h1[32][260];
    int tid = threadIdx.x;
    int base = blockIdx.x * 32;
    for (int i = 0; i < 2; ++i) {
        int f4 = i * 256 + tid;
        int r = f4 >> 4, c4 = f4 & 15;
        float4 v = make_float4(0.f, 0.f, 0.f, 0.f);
        int gr = base + r;
        if (gr < N_) v = *(const float4*)&xres[gr * 64 + c4 * 4];
        *(float4*)&xr[r][c4 * 4] = v;
    }
    __syncthreads();
    if (tid < 32) {
        int r = tid;
        float s = 0.f;
        for (int k = 0; k < 64; ++k) s += xr[r][k];
        float mu = s * (1.0f / 64.0f);
        float v = 0.f;
        for (int k = 0; k < 64; ++k) { float d = xr[r][k] - mu; v += d * d; }
        float rs = rsqrtf(v * (1.0f / 64.0f) + EPS_);
        for (int k = 0; k < 64; ++k)
            xr[r][k] = (xr[r][k] - mu) * rs * gam[k] + bet[k];
    }
    __syncthreads();
    {   // GEMM1 [32x64]@[64x256] -> gelu -> h1
        int tx = tid & 63, ty = tid >> 6;
        int c0 = tx * 4, r0 = ty * 8;
        float acc[8][4];
        for (int r = 0; r < 8; ++r)
            for (int j = 0; j < 4; ++j) acc[r][j] = b1[c0 + j];
        for (int k0 = 0; k0 < 64; k0 += 4) {
            float4 a[8], w[4];
            for (int r = 0; r < 8; ++r) a[r] = *(const float4*)&xr[r0 + r][k0];
            for (int kk = 0; kk < 4; ++kk) w[kk] = *(const float4*)&W1[(k0 + kk) * 256 + c0];
            for (int kk = 0; kk < 4; ++kk)
                for (int r = 0; r < 8; ++r) {
                    float as = (&a[r].x)[kk];
                    acc[r][0] = fmaf(as, w[kk].x, acc[r][0]);
                    acc[r][1] = fmaf(as, w[kk].y, acc[r][1]);
                    acc[r][2] = fmaf(as, w[kk].z, acc[r][2]);
                    acc[r][3] = fmaf(as, w[kk].w, acc[r][3]);
                }
        }
        for (int r = 0; r < 8; ++r)
            for (int j = 0; j < 4; ++j) h1[r0 + r][c0 + j] = gelu_f(acc[r][j]);
    }
    __syncthreads();
    {   // GEMM2 [32x256]@[256x128] -> gelu -> x0
        int tx = tid & 31, ty = tid >> 5;
        int c0 = tx * 4, r0 = ty * 4;
        float acc[4][4];
        for (int r = 0; r < 4; ++r)
            for (int j = 0; j < 4; ++j) acc[r][j] = b2[c0 + j];
        for (int k0 = 0; k0 < 256; k0 += 4) {
            float4 a[4], w[4];
            for (int r = 0; r < 4; ++r) a[r] = *(const float4*)&h1[r0 + r][k0];
            for (int kk = 0; kk < 4; ++kk) w[kk] = *(const float4*)&W2[(k0 + kk) * 128 + c0];
            for (int kk = 0; kk < 4; ++kk)
                for (int r = 0; r < 4; ++r) {
                    float as = (&a[r].x)[kk];
                    acc[r][0] = fmaf(as, w[kk].x, acc[r][0]);
                    acc[r][1] = fmaf(as, w[kk].y, acc[r][1]);
                    acc[r][2] = fmaf(as, w[kk].z, acc[r][2]);
                    acc[r][3] = fmaf(as, w[kk].w, acc[r][3]);
                }
        }
        for (int r = 0; r < 4; ++r) {
            int gr = base + r0 + r;
            if (gr < N_) {
                float4 v = make_float4(gelu_f(acc[r][0]), gelu_f(acc[r][1]),
                                       gelu_f(acc[r][2]), gelu_f(acc[r][3]));
                *(float4*)&x0[(long)gr * 128 + c0] = v;
            }
        }
    }
}

// ---- CSR gather: agg[g] = inv * sum_{src} X[src]; 1 wave = 1 group, 4 edges/iter ----
__global__ __launch_bounds__(256) void k_gather(
    const int* __restrict__ rpA, const int* __restrict__ cnt, const int* __restrict__ csr,
    const float* __restrict__ inv, const float* __restrict__ X, int ldx, float* __restrict__ agg) {
    int tid = threadIdx.x;
    int g = blockIdx.x * 4 + (tid >> 6);
    if (g >= NG_) return;
    int lane = tid & 63;
    int sub = lane >> 4;
    int f = (lane & 15) * 8;
    int start = rpA[g];
    int end = start + cnt[g];
    float4 s0 = make_float4(0.f, 0.f, 0.f, 0.f);
    float4 s1 = make_float4(0.f, 0.f, 0.f, 0.f);
    for (int e = start + sub; e < end; e += 4) {
        int sn = csr[e];
        const float* row = &X[(long)sn * ldx + f];
        const float4 v0 = *(const float4*)row;
        const float4 v1 = *(const float4*)(row + 4);
        s0.x += v0.x; s0.y += v0.y; s0.z += v0.z; s0.w += v0.w;
        s1.x += v1.x; s1.y += v1.y; s1.z += v1.z; s1.w += v1.w;
    }
    s0.x += __shfl_xor(s0.x, 16); s0.y += __shfl_xor(s0.y, 16);
    s0.z += __shfl_xor(s0.z, 16); s0.w += __shfl_xor(s0.w, 16);
    s1.x += __shfl_xor(s1.x, 16); s1.y += __shfl_xor(s1.y, 16);
    s1.z += __shfl_xor(s1.z, 16); s1.w += __shfl_xor(s1.w, 16);
    s0.x += __shfl_xor(s0.x, 32); s0.y += __shfl_xor(s0.y, 32);
    s0.z += __shfl_xor(s0.z, 32); s0.w += __shfl_xor(s0.w, 32);
    s1.x += __shfl_xor(s1.x, 32); s1.y += __shfl_xor(s1.y, 32);
    s1.z += __shfl_xor(s1.z, 32); s1.w += __shfl_xor(s1.w, 32);
    if (sub == 0) {
        float iv = inv[g];
        float* op = &agg[(long)g * 128 + f];
        *(float4*)op = make_float4(s0.x * iv, s0.y * iv, s0.z * iv, s0.w * iv);
        *(float4*)(op + 4) = make_float4(s1.x * iv, s1.y * iv, s1.z * iv, s1.w * iv);
    }
}

// ---- body GEMM: g_out = gelu(sum_t agg_t@(Wl_t/3) + x@Wr_avg + b_avg); cs_l += colsum(g) ----
__global__ __launch_bounds__(256) void k_gemm_body(
    const float* __restrict__ X, int ldx, const float* __restrict__ agg,
    const float* __restrict__ wls_l, const float* __restrict__ wra_l, const float* __restrict__ ba_l,
    float* __restrict__ g_out, float* __restrict__ cs_l) {
    __shared__ float xs[64][132];
    __shared__ float sd[8][128];
    int tid = threadIdx.x;
    int base = blockIdx.x * 64;
    int tx = tid & 31, ty = tid >> 5;
    int c0 = tx * 4, r0 = ty * 8;
    float acc[8][4];
    for (int r = 0; r < 8; ++r)
        for (int j = 0; j < 4; ++j) acc[r][j] = ba_l[c0 + j];
    for (int seg = 0; seg < 4; ++seg) {
        const float* src; long ld;
        if (seg < 3) { src = agg + ((long)seg * N_ + base) * 128; ld = 128; }
        else         { src = X + (long)base * ldx; ld = ldx; }
        __syncthreads();
        for (int i = 0; i < 8; ++i) {
            int f4 = i * 256 + tid;
            int r = f4 >> 5, c4 = f4 & 31;
            float4 v = make_float4(0.f, 0.f, 0.f, 0.f);
            if (base + r < N_) v = *(const float4*)&src[(long)r * ld + c4 * 4];
            *(float4*)&xs[r][c4 * 4] = v;
        }
        __syncthreads();
        const float* W = (seg < 3) ? (wls_l + seg * 16384) : wra_l;
        for (int k0 = 0; k0 < 128; k0 += 4) {
            float4 a[8], w[4];
            for (int r = 0; r < 8; ++r) a[r] = *(const float4*)&xs[r0 + r][k0];
            for (int kk = 0; kk < 4; ++kk) w[kk] = *(const float4*)&W[(k0 + kk) * 128 + c0];
            for (int kk = 0; kk < 4; ++kk)
                for (int r = 0; r < 8; ++r) {
                    float as = (&a[r].x)[kk];
                    acc[r][0] = fmaf(as, w[kk].x, acc[r][0]);
                    acc[r][1] = fmaf(as, w[kk].y, acc[r][1]);
                    acc[r][2] = fmaf(as, w[kk].z, acc[r][2]);
                    acc[r][3] = fmaf(as, w[kk].w, acc[r][3]);
                }
        }
    }
    // epilogue: gelu, store, per-block column sums
    float csum[4] = {0.f, 0.f, 0.f, 0.f};
    for (int r = 0; r < 8; ++r) {
        int gr = base + r0 + r;
        if (gr < N_) {
            float g0 = gelu_f(acc[r][0]), g1 = gelu_f(acc[r][1]);
            float g2 = gelu_f(acc[r][2]), g3 = gelu_f(acc[r][3]);
            *(float4*)&g_out[(long)gr * 128 + c0] = make_float4(g0, g1, g2, g3);
            csum[0] += g0; csum[1] += g1; csum[2] += g2; csum[3] += g3;
        }
    }
    *(float4*)&sd[ty][c0] = make_float4(csum[0], csum[1], csum[2], csum[3]);
    __syncthreads();
    if (tid < 128) {
        float t = 0.f;
        for (int i = 0; i < 8; ++i) t += sd[i][tid];
        atomicAdd(&cs_l[tid], t);
    }
}

// ---------------- GraphNorm: var accumulate (read-only) ----------------
__global__ __launch_bounds__(256) void k_pass2(const float* __restrict__ g,
                                               const float* __restrict__ cs_l,
                                               const float* __restrict__ gsc, float* __restrict__ cq_l) {
    __shared__ float sd[256];
    int tid = threadIdx.x;
    int c = tid & 127, half = tid >> 7;
    int base = blockIdx.x * 128 + half * 64;
    float sm = gsc[c] * (cs_l[c] / 50000.0f);
    float s = 0.f;
    for (int i = 0; i < 64; ++i) {
        int r = base + i;
        if (r < N_) { float o = g[(long)r * 128 + c] - sm; s += o * o; }
    }
    sd[tid] = s;
    __syncthreads();
    if (tid < 128) atomicAdd(&cq_l[c], sd[tid] + sd[tid + 128]);
}
// ---------------- GraphNorm: final scale -> xsave ----------------
__global__ __launch_bounds__(256) void k_pass3(const float* __restrict__ g,
                                               const float* __restrict__ cs_l, const float* __restrict__ cq_l,
                                               const float* __restrict__ gsc,
                                               const float* __restrict__ gw, const float* __restrict__ gb,
                                               float* __restrict__ xs_l) {
    int tid = threadIdx.x;
    int c = tid & 127, half = tid >> 7;
    int base = blockIdx.x * 128 + half * 64;
    float sm = gsc[c] * (cs_l[c] / 50000.0f);
    float var = cq_l[c] / 50000.0f;
    float mul = rsqrtf(var + EPS_) * gw[c];
    float add = gb[c];
    for (int i = 0; i < 64; ++i) {
        int r = base + i;
        if (r < N_) xs_l[(long)r * 384 + c] = (g[(long)r * 128 + c] - sm) * mul + add;
    }
}

// ---------------- head part 1: [N,384]@Wh1 gelu @Wh2 gelu -> h2 (K-tiled, 64 rows) ----------------
__global__ __launch_bounds__(256) void k_head1(const float* __restrict__ xsave,
    const float* __restrict__ Wh1, const float* __restrict__ bh1,
    const float* __restrict__ Wh2, const float* __restrict__ bh2,
    float* __restrict__ h2out) {
    __shared__ float at[64][68];
    __shared__ float h1b[64][104];
    int tid = threadIdx.x;
    int base = blockIdx.x * 64;
    int tx = tid & 31, ty = tid >> 5;
    int c0 = tx * 4, r0 = ty * 8;
    bool valid = (c0 < 100);
    float acc[8][4];
    for (int r = 0; r < 8; ++r)
        for (int j = 0; j < 4; ++j) acc[r][j] = valid ? bh1[c0 + j] : 0.f;
    for (int kt = 0; kt < 6; ++kt) {
        __syncthreads();
        for (int i = 0; i < 4; ++i) {
            int f4 = i * 256 + tid;
            int r = f4 >> 4, c4 = f4 & 15;
            float4 v = make_float4(0.f, 0.f, 0.f, 0.f);
            int gr = base + r;
            if (gr < N_) v = *(const float4*)&xsave[(long)gr * 384 + kt * 64 + c4 * 4];
            *(float4*)&at[r][c4 * 4] = v;
        }
        __syncthreads();
        if (valid) {
            for (int k0 = 0; k0 < 64; k0 += 4) {
                float4 a[8], w[4];
                for (int r = 0; r < 8; ++r) a[r] = *(const float4*)&at[r0 + r][k0];
                for (int kk = 0; kk < 4; ++kk) w[kk] = *(const float4*)&Wh1[(kt * 64 + k0 + kk) * 100 + c0];
                for (int kk = 0; kk < 4; ++kk)
                    for (int r = 0; r < 8; ++r) {
                        float as = (&a[r].x)[kk];
                        acc[r][0] = fmaf(as, w[kk].x, acc[r][0]);
                        acc[r][1] = fmaf(as, w[kk].y, acc[r][1]);
                        acc[r][2] = fmaf(as, w[kk].z, acc[r][2]);
                        acc[r][3] = fmaf(as, w[kk].w, acc[r][3]);
                    }
            }
        }
    }
    __syncthreads();
    if (valid)
        for (int r = 0; r < 8; ++r)
            for (int j = 0; j < 4; ++j) h1b[r0 + r][c0 + j] = gelu_f(acc[r][j]);
    __syncthreads();
    {
        float acc2[8][4];
        for (int r = 0; r < 8; ++r)
            for (int j = 0; j < 4; ++j) acc2[r][j] = valid ? bh2[c0 + j] : 0.f;
        if (valid) {
            for (int k0 = 0; k0 < 100; k0 += 4) {
                float4 a[8], w[4];
                for (int r = 0; r < 8; ++r) a[r] = *(const float4*)&h1b[r0 + r][k0];
                for (int kk = 0; kk < 4; ++kk) w[kk] = *(const float4*)&Wh2[(k0 + kk) * 100 + c0];
                for (int kk = 0; kk < 4; ++kk)
                    for (int r = 0; r < 8; ++r) {
                        float as = (&a[r].x)[kk];
                        acc2[r][0] = fmaf(as, w[kk].x, acc2[r][0]);
                        acc2[r][1] = fmaf(as, w[kk].y, acc2[r][1]);
                        acc2[r][2] = fmaf(as, w[kk].z, acc2[r][2]);
                        acc2[r][3] = fmaf(as, w[kk].w, acc2[r][3]);
                    }
            }
            for (int r = 0; r < 8; ++r) {
                int gr = base + r0 + r;
                if (gr < N_) {
                    float4 v = make_float4(gelu_f(acc2[r][0]), gelu_f(acc2[r][1]),
                                           gelu_f(acc2[r][2]), gelu_f(acc2[r][3]));
                    *(float4*)&h2out[(long)gr * 100 + c0] = v;
                }
            }
        }
    }
}

// ---------------- head part 2 + VQ ----------------
__global__ __launch_bounds__(128) void k_head2(const float* __restrict__ h2,
    const float* __restrict__ xAA,
    const float* __restrict__ Wo1, const float* __restrict__ bo1,
    const float* __restrict__ Wo2, const float* __restrict__ bo2,
    const float* __restrict__ Wo3, const float* __restrict__ bo3,
    const float* __restrict__ cb, float* __restrict__ zq, float* __restrict__ loss) {
    __shared__ __align__(16) float smem[13216];
    float* A  = smem;           // [32][124], also reused as C
    float* B  = smem + 3968;    // [32][104]
    float* XF = smem + 7296;    // [32][36]
    float* CB = smem + 8448;    // [128][36]
    float* CC = smem + 13056;   // [128]
    float* SR = smem + 13184;   // [32]
    int tid = threadIdx.x;
    int base = blockIdx.x * 32;
    for (int i = 0; i < 8; ++i) {
        int f4 = i * 128 + tid;
        int k = f4 >> 3, j4 = f4 & 7;
        float4 v = *(const float4*)&cb[k * 32 + j4 * 4];
        *(float4*)&CB[k * 36 + j4 * 4] = v;
    }
    for (int i = 0; i < 7; ++i) {
        int f4 = i * 128 + tid;
        if (f4 < 800) {
            int r = f4 / 25, c4 = f4 - r * 25;
            float4 v = make_float4(0.f, 0.f, 0.f, 0.f);
            int gr = base + r;
            if (gr < N_) v = *(const float4*)&h2[(long)gr * 100 + c4 * 4];
            *(float4*)&A[r * 124 + c4 * 4] = v;
        }
    }
    for (int i = 0; i < 2; ++i) {
        int f4 = i * 128 + tid;
        if (f4 < 160) {
            int r = f4 / 5, c4 = f4 - r * 5;
            float4 v = make_float4(0.f, 0.f, 0.f, 0.f);
            int gr = base + r;
            if (gr < N_) v = *(const float4*)&xAA[(long)gr * 20 + c4 * 4];
            *(float4*)&A[r * 124 + 100 + c4 * 4] = v;
        }
    }
    __syncthreads();
    if (tid < 128) {
        float s = 0.f;
        for (int j = 0; j < 32; ++j) { float v = CB[tid * 36 + j]; s += v * v; }
        CC[tid] = s;
    }
    int tx = tid & 31, ty = tid >> 5;
    int c0 = tx * 4, r0 = ty * 8;
    bool valid = (c0 < 100);
    {   // GEMM: A[32][120] @ Wo1 -> gelu -> B
        float acc[8][4];
        for (int r = 0; r < 8; ++r)
            for (int j = 0; j < 4; ++j) acc[r][j] = valid ? bo1[c0 + j] : 0.f;
        if (valid) {
            for (int k0 = 0; k0 < 120; k0 += 4) {
                float4 a[8], w[4];
                for (int r = 0; r < 8; ++r) a[r] = *(const float4*)&A[(r0 + r) * 124 + k0];
                for (int kk = 0; kk < 4; ++kk) w[kk] = *(const float4*)&Wo1[(k0 + kk) * 100 + c0];
                for (int kk = 0; kk < 4; ++kk)
                    for (int r = 0; r < 8; ++r) {
                        float as = (&a[r].x)[kk];
                        acc[r][0] = fmaf(as, w[kk].x, acc[r][0]);
                        acc[r][1] = fmaf(as, w[kk].y, acc[r][1]);
                        acc[r][2] = fmaf(as, w[kk].z, acc[r][2]);
                        acc[r][3] = fmaf(as, w[kk].w, acc[r][3]);
                    }
            }
        }
        __syncthreads();
        if (valid)
            for (int r = 0; r < 8; ++r)
                for (int j = 0; j < 4; ++j) B[(r0 + r) * 104 + c0 + j] = gelu_f(acc[r][j]);
    }
    __syncthreads();
    {   // GEMM: B @ Wo2 -> gelu -> C (aliased onto A)
        float acc[8][4];
        for (int r = 0; r < 8; ++r)
            for (int j = 0; j < 4; ++j) acc[r][j] = valid ? bo2[c0 + j] : 0.f;
        if (valid) {
            for (int k0 = 0; k0 < 100; k0 += 4) {
                float4 a[8], w[4];
                for (int r = 0; r < 8; ++r) a[r] = *(const float4*)&B[(r0 + r) * 104 + k0];
                for (int kk = 0; kk < 4; ++kk) w[kk] = *(const float4*)&Wo2[(k0 + kk) * 100 + c0];
                for (int kk = 0; kk < 4; ++kk)
                    for (int r = 0; r < 8; ++r) {
                        float as = (&a[r].x)[kk];
                        acc[r][0] = fmaf(as, w[kk].x, acc[r][0]);
                        acc[r][1] = fmaf(as, w[kk].y, acc[r][1]);
                        acc[r][2] = fmaf(as, w[kk].z, acc[r][2]);
                        acc[r][3] = fmaf(as, w[kk].w, acc[r][3]);
                    }
            }
        }
        __syncthreads();
        if (valid)
            for (int r = 0; r < 8; ++r)
                for (int j = 0; j < 4; ++j) A[(r0 + r) * 124 + c0 + j] = gelu_f(acc[r][j]);
    }
    __syncthreads();
    {   // GEMM: C @ Wo3 -> tanh -> XF
        int c0b = (tid & 7) * 4, rg = tid >> 3;
        int r0b = rg * 2;
        float acc[2][4];
        for (int r = 0; r < 2; ++r)
            for (int j = 0; j < 4; ++j) acc[r][j] = bo3[c0b + j];
        for (int k0 = 0; k0 < 100; k0 += 4) {
            float4 a[2], w[4];
            for (int r = 0; r < 2; ++r) a[r] = *(const float4*)&A[(r0b + r) * 124 + k0];
            for (int kk = 0; kk < 4; ++kk) w[kk] = *(const float4*)&Wo3[(k0 + kk) * 32 + c0b];
            for (int kk = 0; kk < 4; ++kk)
                for (int r = 0; r < 2; ++r) {
                    float as = (&a[r].x)[kk];
                    acc[r][0] = fmaf(as, w[kk].x, acc[r][0]);
                    acc[r][1] = fmaf(as, w[kk].y, acc[r][1]);
                    acc[r][2] = fmaf(as, w[kk].z, acc[r][2]);
                    acc[r][3] = fmaf(as, w[kk].w, acc[r][3]);
                }
        }
        for (int r = 0; r < 2; ++r)
            for (int j = 0; j < 4; ++j) XF[(r0b + r) * 36 + c0b + j] = tanhf(acc[r][j]);
    }
    __syncthreads();
    {   // VQ: 4 threads per node, 32 codes each (interleaved k = kk*4+t4)
        int node = tid >> 2, t4 = tid & 3;
        float4 xv[8];
        for (int j4 = 0; j4 < 8; ++j4) xv[j4] = *(const float4*)&XF[node * 36 + j4 * 4];
        float xx = 0.f;
        for (int j4 = 0; j4 < 8; ++j4)
            xx += xv[j4].x * xv[j4].x + xv[j4].y * xv[j4].y + xv[j4].z * xv[j4].z + xv[j4].w * xv[j4].w;
        float best = 3.4e38f;
        int bidx = 0;
        for (int kk = 0; kk < 32; ++kk) {
            int k = kk * 4 + t4;
            const float* cbr = &CB[k * 36];
            float dot = 0.f;
            for (int j4 = 0; j4 < 8; ++j4) {
                float4 cv = *(const float4*)&cbr[j4 * 4];
                dot += cv.x * xv[j4].x + cv.y * xv[j4].y + cv.z * xv[j4].z + cv.w * xv[j4].w;
            }
            float d = fmaf(-2.0f, dot, xx) + CC[k];
            if (d < best) { best = d; bidx = k; }
        }
        for (int off = 1; off < 4; off <<= 1) {
            float ob = __shfl_xor(best, off);
            int oi = __shfl_xor(bidx, off);
            if (ob < best || (ob == best && oi < bidx)) { best = ob; bidx = oi; }
        }
        int gr = base + node;
        if (t4 == 0) {
            float s = 0.f;
            if (gr < N_) {
                const float* q = &CB[bidx * 36];
                for (int j4 = 0; j4 < 8; ++j4) {
                    float4 qv = *(const float4*)&q[j4 * 4];
                    *(float4*)&zq[(long)gr * 32 + j4 * 4] = qv;
                    float4 xvv = xv[j4];
                    float d0 = qv.x - xvv.x, d1 = qv.y - xvv.y, d2 = qv.z - xvv.z, d3 = qv.w - xvv.w;
                    s += d0 * d0 + d1 * d1 + d2 * d2 + d3 * d3;
                }
            }
            SR[node] = s;
        }
    }
    __syncthreads();
    if (tid == 0) {
        float S = 0.f;
        for (int i = 0; i < 32; ++i) S += SR[i];
        atomicAdd(loss, S);
    }
}

__global__ void k_fin(float* dout, const float* loss) {
    if (threadIdx.x == 0 && blockIdx.x == 0)
        dout[(long)N_ * 32] = 1.25f * (loss[0] / 1600000.0f);
}

extern "C" void kernel_launch(void* const* d_in, const int* in_sizes, int n_in,
                              void* d_out, int out_size, void* d_ws, size_t ws_size,
                              hipStream_t stream) {
    const float* x_res = (const float*)d_in[0];
    const float* x_AA  = (const float*)d_in[1];
    const int*   EI    = (const int*)d_in[2];
    const float* ln_g  = (const float*)d_in[3];
    const float* ln_b  = (const float*)d_in[4];
    const float* W1    = (const float*)d_in[5];
    const float* b1    = (const float*)d_in[6];
    const float* W2    = (const float*)d_in[7];
    const float* b2    = (const float*)d_in[8];
    const float* sWl   = (const float*)d_in[9];
    const float* sWr   = (const float*)d_in[10];
    const float* sb    = (const float*)d_in[11];
    const float* gnw   = (const float*)d_in[12];
    const float* gnb   = (const float*)d_in[13];
    const float* gns   = (const float*)d_in[14];
    const float* Wh1   = (const float*)d_in[15];
    const float* bh1   = (const float*)d_in[16];
    const float* Wh2   = (const float*)d_in[17];
    const float* bh2   = (const float*)d_in[18];
    const float* Wo1   = (const float*)d_in[19];
    const float* bo1   = (const float*)d_in[20];
    const float* Wo2   = (const float*)d_in[21];
    const float* bo2   = (const float*)d_in[22];
    const float* Wo3   = (const float*)d_in[23];
    const float* bo3   = (const float*)d_in[24];
    const float* cbk   = (const float*)d_in[25];
    float* out = (float*)d_out;

    float* ws    = (float*)d_ws;
    float* xsave = ws;                               // N*384
    float* x0    = xsave + (size_t)N_ * 384;         // N*128
    float* agg   = x0 + (size_t)N_ * 128;            // 3*N*128
    float* gbuf  = agg + (size_t)3 * N_ * 128;       // N*128 (gelu of conv out)
    float* wls   = gbuf + (size_t)N_ * 128;          // 147456
    float* wra   = wls + 147456;                     // 49152
    float* ba    = wra + 49152;                      // 384
    // zero-init region: [cursor 1][loss 1][cs 3*128][cq 3*128]
    int*   cursor = (int*)(ba + 384);                // 1
    float* loss  = (float*)(cursor + 1);             // 1
    float* cs    = loss + 1;                         // 3*128
    float* cq    = cs + 384;                         // 3*128
    int*   head  = (int*)(cq + 384);                 // NG_  (memset 0xFF)
    int*   nxt   = head + NG_;                       // T_*E_
    int*   cnt   = nxt + (size_t)T_ * E_;            // NG_
    int*   rpA   = cnt + NG_;                        // NG_
    float* inv   = (float*)(rpA + NG_);              // NG_
    int*   csr   = (int*)(inv + NG_);                // T_*E_
    float* h2    = agg + (size_t)N_ * 128;           // reuse agg slice 1 (dead after body)

    hipMemsetAsync(cursor, 0, 770 * sizeof(int), stream);
    hipMemsetAsync(head, 0xFF, NG_ * sizeof(int), stream);

    k_prep<<<576, 256, 0, stream>>>(sWl, sWr, sb, wls, wra, ba);
    k_link<<<(T_ * E_ + 255) / 256, 256, 0, stream>>>(EI, head, nxt);
    k_compact<<<(NG_ + 255) / 256, 256, 0, stream>>>(EI, head, nxt, cursor, cnt, rpA, inv, csr);
    k_inmlp<<<(N_ + 31) / 32, 256, 0, stream>>>(x_res, ln_g, ln_b, W1, b1, W2, b2, x0);

    for (int l = 0; l < 3; ++l) {
        const float* X = (l == 0) ? x0 : (xsave + (size_t)(l - 1) * 128);
        int ldx = (l == 0) ? 128 : 384;
        k_gather<<<NG_ / 4, 256, 0, stream>>>(rpA, cnt, csr, inv, X, ldx, agg);
        k_gemm_body<<<(N_ + 63) / 64, 256, 0, stream>>>(X, ldx, agg,
            wls + (size_t)l * 3 * 16384, wra + (size_t)l * 16384, ba + l * 128,
            gbuf, cs + l * 128);
        k_pass2<<<(N_ + 127) / 128, 256, 0, stream>>>(gbuf, cs + l * 128, gns + l * 128, cq + l * 128);
        k_pass3<<<(N_ + 127) / 128, 256, 0, stream>>>(gbuf, cs + l * 128, cq + l * 128,
                                                      gns + l * 128, gnw + l * 128, gnb + l * 128,
                                                      xsave + (size_t)l * 128);
    }
    k_head1<<<(N_ + 63) / 64, 256, 0, stream>>>(xsave, Wh1, bh1, Wh2, bh2, h2);
    k_head2<<<(N_ + 31) / 32, 128, 0, stream>>>(h2, x_AA, Wo1, bo1, Wo2, bo2, Wo3, bo3,
                                                cbk, out, loss);
    k_fin<<<1, 64, 0, stream>>>(out, loss);
}